// Round 2
// baseline (1111.094 us; speedup 1.0000x reference)
//
#include <hip/hip_runtime.h>
#include <hip/hip_bf16.h>
#include <cstdint>
#include <cstddef>

// ButterflyLayer2D on MI355X.
// Pipeline: stage0 patch-embed -> 6 butterfly levels (each a per-site
// (B x 256)x(256 x 64) GEMM + bias + relu) -> final per-(u,v) GEMM.
// Input dtype (f32 vs bf16, harness-dependent) detected on-device; flag in
// d_ws[0]. Intermediates are f32 in d_ws. Output written in detected dtype.

static __device__ __forceinline__ float b2f(const __hip_bfloat16 x) {
    return __bfloat162float(x);
}

// ---------------------------------------------------------------------------
// Dtype detection: interpret first 64 words of in_data as f32. True f32
// normals are all within [1e-8, 1e4]. bf16-pair words have f32-exponent
// = (bf16_exp<<1 | mant_msb) ~ 252..255 -> huge/inf/denormal -> implausible.
// flag: 0 = f32, 1 = bf16.
// ---------------------------------------------------------------------------
__global__ void k_detect(const uint32_t* __restrict__ in, int* __restrict__ flag) {
    const int t = threadIdx.x;  // 64 threads
    const float v = __uint_as_float(in[t]);
    const bool plaus = (v == 0.0f) || (fabsf(v) > 1e-8f && fabsf(v) < 1e4f);
    const unsigned long long m = __ballot(plaus);
    if (t == 0) *flag = (__popcll(m) >= 48) ? 0 : 1;
}

// ---------------------------------------------------------------------------
// Stage 0: x0[b, X, Y, c] = relu( sum_{p,q} in[b, 4X+p, 4Y+q] * F[p,q,c] + b[c] )
// grid.x = Bc*64 (one block per (b_local, X) row), 256 threads.
// ---------------------------------------------------------------------------
__global__ __launch_bounds__(256) void k_stage0(
    const void* __restrict__ in_data,  // (128,256,256,1)
    const void* __restrict__ filt,     // (4,4,1,64)
    const void* __restrict__ bias,     // (64)
    float* __restrict__ x0,            // (Bc,64,64,64)
    const int* __restrict__ flag,
    int b_off)
{
    const int isbf = *flag;
    const int blk = blockIdx.x;
    const int X  = blk & 63;
    const int bl = blk >> 6;          // local batch
    const int bg = bl + b_off;        // global batch

    __shared__ float sIn[4][256];
    __shared__ float sF[16][64];
    __shared__ float sB[64];

    const int t = threadIdx.x;
    const size_t srow = ((size_t)bg * 256 + (size_t)X * 4) * 256;

    if (isbf) {
        const __hip_bfloat16* src = (const __hip_bfloat16*)in_data + srow;
        #pragma unroll
        for (int i = 0; i < 4; i++) {
            int flat = i * 256 + t;            // 1024 elems
            int p = flat >> 8, col = flat & 255;
            sIn[p][col] = b2f(src[(size_t)p * 256 + col]);
        }
        const __hip_bfloat16* fsrc = (const __hip_bfloat16*)filt;
        #pragma unroll
        for (int i = 0; i < 4; i++) {
            int flat = i * 256 + t;
            sF[flat >> 6][flat & 63] = b2f(fsrc[flat]);
        }
        if (t < 64) sB[t] = b2f(((const __hip_bfloat16*)bias)[t]);
    } else {
        const float* src = (const float*)in_data + srow;
        #pragma unroll
        for (int i = 0; i < 4; i++) {
            int flat = i * 256 + t;
            int p = flat >> 8, col = flat & 255;
            sIn[p][col] = src[(size_t)p * 256 + col];
        }
        const float* fsrc = (const float*)filt;
        #pragma unroll
        for (int i = 0; i < 4; i++) {
            int flat = i * 256 + t;
            sF[flat >> 6][flat & 63] = fsrc[flat];
        }
        if (t < 64) sB[t] = ((const float*)bias)[t];
    }
    __syncthreads();

    float* dst = x0 + ((size_t)bl * 64 + X) * 64 * 64;
    #pragma unroll
    for (int i = 0; i < 16; i++) {
        int flat = i * 256 + t;            // 4096 outputs (Y, c)
        int c = flat & 63, Y = flat >> 6;
        float acc = sB[c];
        #pragma unroll
        for (int p = 0; p < 4; p++) {
            #pragma unroll
            for (int q = 0; q < 4; q++) {
                acc = fmaf(sIn[p][Y * 4 + q], sF[p * 4 + q][c], acc);
            }
        }
        dst[(size_t)Y * 64 + c] = fmaxf(acc, 0.f);
    }
}

// ---------------------------------------------------------------------------
// Butterfly level: per site (u,v,h,w):
//   out[b,o] = relu( sum_{x,y,c} in[u',v',b,2h+x,2w+y,c] * f[u,v,x,y,c,o] + b[u,v,o] )
// Block tile: up to BTILE batches x 64 outputs. 256 threads,
// micro-tile (BTILE/32) b x 8 o. grid.x = Nu*Nv*H*W.
// ---------------------------------------------------------------------------
template <int BTILE>
__global__ __launch_bounds__(256) void k_level(
    const float* __restrict__ xin,
    const void* __restrict__ f,     // (n,n,2,2,64,64)
    const void* __restrict__ bias,  // (n,n,64)
    float* __restrict__ xout,
    const int* __restrict__ flag,
    int Nv_out, int H_out, int W_out, int Bc, int repeat)
{
    constexpr int BPT = BTILE / 32;
    const int isbf = *flag;

    int idx = blockIdx.x;
    const int w = idx % W_out; idx /= W_out;
    const int h = idx % H_out; idx /= H_out;
    const int v = idx % Nv_out;
    const int u = idx / Nv_out;

    const int u_in = repeat ? (u >> 1) : u;
    const int v_in = repeat ? (v >> 1) : v;
    const int Nv_in = repeat ? (Nv_out >> 1) : Nv_out;
    const int H_in = H_out * 2, W_in = W_out * 2;

    __shared__ float sA[BTILE][65];   // [b][c], +1 pad: <=2-way conflicts (free)
    __shared__ float sW[64][64];      // [c][o]

    const int t = threadIdx.x;
    const int tb = t >> 3;            // 0..31 -> batch group
    const int to = t & 7;             // 0..7  -> output group (8 o's)

    float acc[BPT][8];
    #pragma unroll
    for (int i = 0; i < BPT; i++)
        #pragma unroll
        for (int j = 0; j < 8; j++) acc[i][j] = 0.f;

    const size_t bstride = (size_t)H_in * W_in * 64;
    const size_t uvb = (size_t)(u_in * Nv_in + v_in) * Bc;
    const size_t fbase = (size_t)(u * Nv_out + v) * 16384;

    for (int xy = 0; xy < 4; xy++) {
        const int xx = xy >> 1, yy = xy & 1;
        const float* src = xin + ((uvb * H_in + (2 * h + xx)) * W_in + (2 * w + yy)) * 64;

        // Stage A tile: BTILE x 64 f32, float4 loads (coalesced); clamp b < Bc.
        #pragma unroll
        for (int i = 0; i < BTILE / 16; i++) {
            int flat = i * 256 + t;          // BTILE*16 float4s
            int c4 = flat & 15, b = flat >> 4;
            int bc = b < Bc ? b : (Bc - 1);
            float4 val = *(const float4*)(src + (size_t)bc * bstride + c4 * 4);
            sA[b][c4 * 4 + 0] = val.x;
            sA[b][c4 * 4 + 1] = val.y;
            sA[b][c4 * 4 + 2] = val.z;
            sA[b][c4 * 4 + 3] = val.w;
        }
        // Stage W tile: 64x64 -> f32
        const size_t foff = fbase + (size_t)xy * 4096;
        if (isbf) {
            const __hip_bfloat16* fsrc = (const __hip_bfloat16*)f + foff;
            #pragma unroll
            for (int i = 0; i < 16; i++) {
                int flat = i * 256 + t;
                sW[flat >> 6][flat & 63] = b2f(fsrc[flat]);
            }
        } else {
            const float* fsrc = (const float*)f + foff;
            #pragma unroll
            for (int i = 0; i < 16; i++) {
                int flat = i * 256 + t;
                sW[flat >> 6][flat & 63] = fsrc[flat];
            }
        }
        __syncthreads();

        #pragma unroll 8
        for (int c = 0; c < 64; c++) {
            const float4 w0 = *(const float4*)&sW[c][to * 8];
            const float4 w1 = *(const float4*)&sW[c][to * 8 + 4];
            #pragma unroll
            for (int i = 0; i < BPT; i++) {
                const float a = sA[tb * BPT + i][c];
                acc[i][0] = fmaf(a, w0.x, acc[i][0]);
                acc[i][1] = fmaf(a, w0.y, acc[i][1]);
                acc[i][2] = fmaf(a, w0.z, acc[i][2]);
                acc[i][3] = fmaf(a, w0.w, acc[i][3]);
                acc[i][4] = fmaf(a, w1.x, acc[i][4]);
                acc[i][5] = fmaf(a, w1.y, acc[i][5]);
                acc[i][6] = fmaf(a, w1.z, acc[i][6]);
                acc[i][7] = fmaf(a, w1.w, acc[i][7]);
            }
        }
        __syncthreads();
    }

    // Epilogue: + bias, relu, store f32
    float bv[8];
    const size_t boff = (size_t)(u * Nv_out + v) * 64 + to * 8;
    if (isbf) {
        const __hip_bfloat16* bb = (const __hip_bfloat16*)bias + boff;
        #pragma unroll
        for (int j = 0; j < 8; j++) bv[j] = b2f(bb[j]);
    } else {
        const float* bb = (const float*)bias + boff;
        #pragma unroll
        for (int j = 0; j < 8; j++) bv[j] = bb[j];
    }

    const size_t ostride = (size_t)H_out * W_out * 64;
    float* dst = xout + (((size_t)(u * Nv_out + v) * Bc) * H_out + h) * W_out * 64
               + (size_t)w * 64 + to * 8;
    #pragma unroll
    for (int i = 0; i < BPT; i++) {
        const int b = tb * BPT + i;
        if (b < Bc) {
            float4 o0, o1;
            o0.x = fmaxf(acc[i][0] + bv[0], 0.f);
            o0.y = fmaxf(acc[i][1] + bv[1], 0.f);
            o0.z = fmaxf(acc[i][2] + bv[2], 0.f);
            o0.w = fmaxf(acc[i][3] + bv[3], 0.f);
            o1.x = fmaxf(acc[i][4] + bv[4], 0.f);
            o1.y = fmaxf(acc[i][5] + bv[5], 0.f);
            o1.z = fmaxf(acc[i][6] + bv[6], 0.f);
            o1.w = fmaxf(acc[i][7] + bv[7], 0.f);
            float* dp = dst + (size_t)b * ostride;
            *(float4*)(dp)     = o0;
            *(float4*)(dp + 4) = o1;
        }
    }
}

// ---------------------------------------------------------------------------
// Final: out[b, u*8+ou, v*8+ov, r] = sum_c feats[u,v,b,c] * Wd[u,v,r,c,ou*8+ov]
// grid.x = 64 (u,v), grid.y = max(Bc/32,1), 256 threads.
// ---------------------------------------------------------------------------
__global__ __launch_bounds__(256) void k_final(
    const float* __restrict__ feats,     // (8,8,Bc,64)
    const void* __restrict__ Wd,         // (8,8,2,64,64)
    void* __restrict__ out,              // (128,64,64,2)
    const int* __restrict__ flag,
    int Bc, int b_off)
{
    const int isbf = *flag;
    const int uv = blockIdx.x;
    const int u = uv >> 3, v = uv & 7;
    const int b0 = blockIdx.y * 32;

    __shared__ float sF[32][64];
    __shared__ float sW[2][64][64];

    const int t = threadIdx.x;

    const float* fsrc = feats + (size_t)uv * Bc * 64;
    #pragma unroll
    for (int i = 0; i < 8; i++) {
        int flat = i * 256 + t;               // 2048 = 32 rows x 64
        int row = flat >> 6;
        int brow = b0 + row;
        if (brow >= Bc) brow = Bc - 1;        // clamp (reads only)
        sF[row][flat & 63] = fsrc[(size_t)brow * 64 + (flat & 63)];
    }
    const size_t woff = (size_t)uv * 2 * 64 * 64;
    if (isbf) {
        const __hip_bfloat16* wsrc = (const __hip_bfloat16*)Wd + woff;
        #pragma unroll
        for (int i = 0; i < 32; i++) {
            int flat = i * 256 + t;           // 8192, layout (r,c,k) flat
            ((float*)sW)[flat] = b2f(wsrc[flat]);
        }
    } else {
        const float* wsrc = (const float*)Wd + woff;
        #pragma unroll
        for (int i = 0; i < 32; i++) {
            int flat = i * 256 + t;
            ((float*)sW)[flat] = wsrc[flat];
        }
    }
    __syncthreads();

    #pragma unroll
    for (int i = 0; i < 16; i++) {
        int flat = i * 256 + t;               // 4096 = 32b * 2r * 64k
        int k = flat & 63;
        int r = (flat >> 6) & 1;
        int b = flat >> 7;
        if (b0 + b >= Bc) continue;
        float acc = 0.f;
        #pragma unroll 8
        for (int c = 0; c < 64; c++) acc = fmaf(sF[b][c], sW[r][c][k], acc);
        const int bg = b_off + b0 + b;
        const int ou = k >> 3, ov = k & 7;
        const size_t oidx = (((size_t)bg * 64 + (u * 8 + ou)) * 64 + (v * 8 + ov)) * 2 + r;
        if (isbf) ((__hip_bfloat16*)out)[oidx] = __float2bfloat16(acc);
        else      ((float*)out)[oidx] = acc;
    }
}

// ---------------------------------------------------------------------------
extern "C" void kernel_launch(void* const* d_in, const int* in_sizes, int n_in,
                              void* d_out, int out_size, void* d_ws, size_t ws_size,
                              hipStream_t stream)
{
    (void)in_sizes; (void)n_in; (void)out_size;

    const void* in_data = d_in[0];
    const void* filt    = d_in[1];
    const void* bias0   = d_in[2];
    const void* fl[7];
    const void* bl[7];
    for (int l = 1; l <= 6; l++) {
        fl[l] = d_in[1 + 2 * l];
        bl[l] = d_in[2 + 2 * l];
    }
    const void* Wd = d_in[15];

    const int Bfull = 128;
    const size_t perB = (size_t)64 * 64 * 64;   // f32 elems per batch per buffer
    const size_t flagBytes = 256;

    // Pick largest batch chunk whose double buffer fits in d_ws (after flag).
    const size_t avail = ws_size > flagBytes ? ws_size - flagBytes : 0;
    int Bc = 0;
    for (int c = 128; c >= 1; c >>= 1) {
        if ((size_t)2 * c * perB * sizeof(float) <= avail) { Bc = c; break; }
    }
    if (Bc == 0) return;  // workspace unusably small

    int* flag = (int*)d_ws;
    float* bufA = (float*)((char*)d_ws + flagBytes);
    float* bufB = bufA + (size_t)Bc * perB;

    k_detect<<<dim3(1), 64, 0, stream>>>((const uint32_t*)in_data, flag);

    for (int b_off = 0; b_off < Bfull; b_off += Bc) {
        k_stage0<<<dim3(Bc * 64), 256, 0, stream>>>(in_data, filt, bias0, bufA, flag, b_off);

        float* cur = bufA;
        float* nxt = bufB;
        for (int lvl = 1; lvl <= 6; lvl++) {
            const int Nu = 1 << (lvl < 3 ? lvl : 3);
            const int H  = 64 >> lvl;
            const int rep = (lvl <= 3) ? 1 : 0;
            dim3 grid(Nu * Nu * H * H);
            if (Bc >= 128)
                k_level<128><<<grid, 256, 0, stream>>>(cur, fl[lvl], bl[lvl], nxt, flag, Nu, H, H, Bc, rep);
            else if (Bc >= 64)
                k_level<64><<<grid, 256, 0, stream>>>(cur, fl[lvl], bl[lvl], nxt, flag, Nu, H, H, Bc, rep);
            else
                k_level<32><<<grid, 256, 0, stream>>>(cur, fl[lvl], bl[lvl], nxt, flag, Nu, H, H, Bc, rep);
            float* tmp = cur; cur = nxt; nxt = tmp;
        }

        dim3 fgrid(64, (Bc >= 32) ? (Bc / 32) : 1);
        k_final<<<fgrid, 256, 0, stream>>>(cur, Wd, d_out, flag, Bc, b_off);
    }
}

// Round 3
// 359.170 us; speedup vs baseline: 3.0935x; 3.0935x over previous
//
#include <hip/hip_runtime.h>
#include <hip/hip_bf16.h>
#include <cstdint>
#include <cstddef>

// ButterflyLayer2D on MI355X.
// stage0 (VALU f32 -> bf16) -> 6 butterfly levels as bf16 MFMA GEMMs
// (M=128 batch, N=64 out, K=256 = 4 taps x 64c, f32 accum) -> final VALU GEMM.
// Intermediates bf16 in d_ws. External weights f32 or bf16 (flag-detected),
// converted to bf16 during LDS staging.

typedef __attribute__((ext_vector_type(8))) short short8;
typedef __attribute__((ext_vector_type(4))) float f32x4;
typedef unsigned short ushort_t;

static __device__ __forceinline__ float b2f(const __hip_bfloat16 x) {
    return __bfloat162float(x);
}
static __device__ __forceinline__ ushort_t f2bf(float x) {
    __hip_bfloat16 h = __float2bfloat16(x);
    ushort_t u;
    __builtin_memcpy(&u, &h, 2);
    return u;
}

// ---------------------------------------------------------------------------
// Dtype detection (flag: 0 = f32, 1 = bf16) — worked in round 2.
// ---------------------------------------------------------------------------
__global__ void k_detect(const uint32_t* __restrict__ in, int* __restrict__ flag) {
    const int t = threadIdx.x;  // 64 threads
    const float v = __uint_as_float(in[t]);
    const bool plaus = (v == 0.0f) || (fabsf(v) > 1e-8f && fabsf(v) < 1e4f);
    const unsigned long long m = __ballot(plaus);
    if (t == 0) *flag = (__popcll(m) >= 48) ? 0 : 1;
}

// ---------------------------------------------------------------------------
// Stage 0: x0[b, X, Y, c] = relu( sum_{p,q} in[b,4X+p,4Y+q] * F[p,q,c] + b[c] )
// grid.x = Bc*64, 256 threads. Output bf16.
// ---------------------------------------------------------------------------
__global__ __launch_bounds__(256) void k_stage0(
    const void* __restrict__ in_data,  // (128,256,256,1)
    const void* __restrict__ filt,     // (4,4,1,64)
    const void* __restrict__ bias,     // (64)
    __hip_bfloat16* __restrict__ x0,   // (Bc,64,64,64) bf16
    const int* __restrict__ flag,
    int b_off)
{
    const int isbf = *flag;
    const int blk = blockIdx.x;
    const int X  = blk & 63;
    const int bl = blk >> 6;
    const int bg = bl + b_off;

    __shared__ float sIn[4][256];
    __shared__ float sF[16][64];
    __shared__ float sB[64];

    const int t = threadIdx.x;
    const size_t srow = ((size_t)bg * 256 + (size_t)X * 4) * 256;

    if (isbf) {
        const __hip_bfloat16* src = (const __hip_bfloat16*)in_data + srow;
        #pragma unroll
        for (int i = 0; i < 4; i++) {
            int flat = i * 256 + t;
            int p = flat >> 8, col = flat & 255;
            sIn[p][col] = b2f(src[(size_t)p * 256 + col]);
        }
        const __hip_bfloat16* fsrc = (const __hip_bfloat16*)filt;
        #pragma unroll
        for (int i = 0; i < 4; i++) {
            int flat = i * 256 + t;
            sF[flat >> 6][flat & 63] = b2f(fsrc[flat]);
        }
        if (t < 64) sB[t] = b2f(((const __hip_bfloat16*)bias)[t]);
    } else {
        const float* src = (const float*)in_data + srow;
        #pragma unroll
        for (int i = 0; i < 4; i++) {
            int flat = i * 256 + t;
            int p = flat >> 8, col = flat & 255;
            sIn[p][col] = src[(size_t)p * 256 + col];
        }
        const float* fsrc = (const float*)filt;
        #pragma unroll
        for (int i = 0; i < 4; i++) {
            int flat = i * 256 + t;
            sF[flat >> 6][flat & 63] = fsrc[flat];
        }
        if (t < 64) sB[t] = ((const float*)bias)[t];
    }
    __syncthreads();

    __hip_bfloat16* dst = x0 + ((size_t)bl * 64 + X) * 64 * 64;
    #pragma unroll
    for (int i = 0; i < 16; i++) {
        int flat = i * 256 + t;
        int c = flat & 63, Y = flat >> 6;
        float acc = sB[c];
        #pragma unroll
        for (int p = 0; p < 4; p++) {
            #pragma unroll
            for (int q = 0; q < 4; q++) {
                acc = fmaf(sIn[p][Y * 4 + q], sF[p * 4 + q][c], acc);
            }
        }
        dst[(size_t)Y * 64 + c] = __float2bfloat16(fmaxf(acc, 0.f));
    }
}

// ---------------------------------------------------------------------------
// Butterfly level, MFMA version. Per site (u,v,h,w):
//   out[b,o] = relu( sum_{x,y,c} in[.., 2h+x, 2w+y, c] * f[u,v,x,y,c,o] + b[u,v,o] )
// Block = 128 b x 64 o tile, 256 threads (4 waves); wave covers 32 b rows.
// mfma_f32_16x16x32_bf16: A[m=lane&15][k=(lane>>4)*8+j], B[k][n=lane&15],
// D col=lane&15, row=(lane>>4)*4+reg.  LDS holds fragment-major bf16 tiles
// (conflict-free ds_read_b128). K per tap = 64 -> 2 k-steps.
// ---------------------------------------------------------------------------
__global__ __launch_bounds__(256) void k_level(
    const __hip_bfloat16* __restrict__ xin,
    const void* __restrict__ f,     // (n,n,2,2,64,64)
    const void* __restrict__ bias,  // (n,n,64)
    __hip_bfloat16* __restrict__ xout,
    const int* __restrict__ flag,
    int Nv_out, int H_out, int W_out, int Bc, int repeat)
{
    const int isbf = *flag;
    int idx = blockIdx.x;
    const int w = idx % W_out; idx /= W_out;
    const int h = idx % H_out; idx /= H_out;
    const int v = idx % Nv_out;
    const int u = idx / Nv_out;

    const int u_in = repeat ? (u >> 1) : u;
    const int v_in = repeat ? (v >> 1) : v;
    const int Nv_in = repeat ? (Nv_out >> 1) : Nv_out;
    const int H_in = H_out * 2, W_in = W_out * 2;

    // sA: 16 slots [ks*8+fm] x 64 lanes x 8 bf16 = 8192 ushorts (16 KB)
    // sB: 8 slots  [ks*4+fn] x 64 lanes x 8 bf16 = 4096 ushorts (8 KB)
    // epilogue reuses smem as out-tile 128 x (stride 72) ushorts (<= 12288)
    __shared__ ushort_t smem[12288];
    ushort_t* sA = smem;
    ushort_t* sB = smem + 8192;
    __shared__ float sBias[64];

    const int t = threadIdx.x;
    const int wave = t >> 6, lane = t & 63;
    const int lm = lane & 15, lq = lane >> 4;

    if (t < 64) {
        const size_t boff = (size_t)(u * Nv_out + v) * 64 + t;
        sBias[t] = isbf ? b2f(((const __hip_bfloat16*)bias)[boff])
                        : ((const float*)bias)[boff];
    }

    const f32x4 zero = {0.f, 0.f, 0.f, 0.f};
    f32x4 acc[2][4];
    #pragma unroll
    for (int i = 0; i < 2; i++)
        #pragma unroll
        for (int j = 0; j < 4; j++) acc[i][j] = zero;

    const size_t bstride = (size_t)H_in * W_in * 64;
    const size_t uvb = (size_t)(u_in * Nv_in + v_in) * Bc;
    const size_t fbase = (size_t)(u * Nv_out + v) * 16384;

    for (int xy = 0; xy < 4; xy++) {
        const int xx = xy >> 1, yy = xy & 1;
        const __hip_bfloat16* src =
            xin + ((uvb * H_in + (2 * h + xx)) * W_in + (2 * w + yy)) * 64;

        // --- stage A: 1024 tasks of one k-octet (8 bf16 = 16 B) each ---
        #pragma unroll
        for (int i = 0; i < 4; i++) {
            int task = i * 256 + t;
            int oct = task & 7, m = task >> 3;
            int mc = m < Bc ? m : (Bc - 1);
            uint4 val = *(const uint4*)(src + (size_t)mc * bstride + oct * 8);
            int ks = oct >> 2;
            int ln = (m & 15) | ((oct & 3) << 4);
            *(uint4*)&sA[((((ks << 3) + (m >> 4)) << 6) + ln) * 8] = val;
        }
        // --- stage W: 512 tasks, each packs 8 strided c for one o ---
        if (isbf) {
            const ushort_t* fw = (const ushort_t*)f + fbase + (size_t)xy * 4096;
            #pragma unroll
            for (int i = 0; i < 2; i++) {
                int task = i * 256 + t;
                int o = task & 63, oct = task >> 6;
                ushort_t pk[8];
                #pragma unroll
                for (int j = 0; j < 8; j++) pk[j] = fw[(oct * 8 + j) * 64 + o];
                int ks = oct >> 2, fn = o >> 4;
                int ln = (o & 15) | ((oct & 3) << 4);
                *(uint4*)&sB[((((ks << 2) + fn) << 6) + ln) * 8] = *(uint4*)pk;
            }
        } else {
            const float* fw = (const float*)f + fbase + (size_t)xy * 4096;
            #pragma unroll
            for (int i = 0; i < 2; i++) {
                int task = i * 256 + t;
                int o = task & 63, oct = task >> 6;
                ushort_t pk[8];
                #pragma unroll
                for (int j = 0; j < 8; j++) pk[j] = f2bf(fw[(oct * 8 + j) * 64 + o]);
                int ks = oct >> 2, fn = o >> 4;
                int ln = (o & 15) | ((oct & 3) << 4);
                *(uint4*)&sB[((((ks << 2) + fn) << 6) + ln) * 8] = *(uint4*)pk;
            }
        }
        __syncthreads();

        // --- compute: 2 k-steps x (2 m-frags x 4 n-frags) mfma ---
        #pragma unroll
        for (int ks = 0; ks < 2; ks++) {
            short8 a0 = *(const short8*)&sA[((((ks << 3) + (wave << 1) + 0) << 6) + lane) * 8];
            short8 a1 = *(const short8*)&sA[((((ks << 3) + (wave << 1) + 1) << 6) + lane) * 8];
            #pragma unroll
            for (int fn = 0; fn < 4; fn++) {
                short8 bv = *(const short8*)&sB[((((ks << 2) + fn) << 6) + lane) * 8];
                acc[0][fn] = __builtin_amdgcn_mfma_f32_16x16x32_bf16(a0, bv, acc[0][fn], 0, 0, 0);
                acc[1][fn] = __builtin_amdgcn_mfma_f32_16x16x32_bf16(a1, bv, acc[1][fn], 0, 0, 0);
            }
        }
        __syncthreads();
    }

    // --- epilogue: +bias, relu, bf16, LDS transpose, vector store ---
    float bv4[4];
    #pragma unroll
    for (int fn = 0; fn < 4; fn++) bv4[fn] = sBias[fn * 16 + lm];

    ushort_t* sOut = smem;            // 128 rows x stride 72 (9216 <= 12288)
    #pragma unroll
    for (int fml = 0; fml < 2; fml++) {
        const int mbase = wave * 32 + fml * 16 + lq * 4;
        #pragma unroll
        for (int fn = 0; fn < 4; fn++) {
            #pragma unroll
            for (int r = 0; r < 4; r++) {
                float vv = fmaxf(acc[fml][fn][r] + bv4[fn], 0.f);
                sOut[(mbase + r) * 72 + fn * 16 + lm] = f2bf(vv);
            }
        }
    }
    __syncthreads();

    const size_t obase = ((size_t)(u * Nv_out + v) * Bc) * H_out * W_out * 64
                       + ((size_t)h * W_out + w) * 64;
    const size_t ostride = (size_t)H_out * W_out * 64;
    #pragma unroll
    for (int i = 0; i < 4; i++) {
        int task = i * 256 + t;
        int ch = task & 7, m = task >> 3;
        if (m < Bc) {
            __hip_bfloat16* dst = xout + obase + (size_t)m * ostride + ch * 8;
            *(uint4*)dst = *(const uint4*)&sOut[m * 72 + ch * 8];
        }
    }
}

// ---------------------------------------------------------------------------
// Final: out[b, u*8+ou, v*8+ov, r] = sum_c feats[u,v,b,c] * Wd[u,v,r,c,ou*8+ov]
// grid.x = 64 (u,v), grid.y = max(Bc/32,1), 256 threads. VALU f32.
// ---------------------------------------------------------------------------
__global__ __launch_bounds__(256) void k_final(
    const __hip_bfloat16* __restrict__ feats,  // (8,8,Bc,64) bf16
    const void* __restrict__ Wd,               // (8,8,2,64,64)
    void* __restrict__ out,                    // (128,64,64,2)
    const int* __restrict__ flag,
    int Bc, int b_off)
{
    const int isbf = *flag;
    const int uv = blockIdx.x;
    const int u = uv >> 3, v = uv & 7;
    const int b0 = blockIdx.y * 32;

    __shared__ float sF[32][64];
    __shared__ float sW[2][64][64];

    const int t = threadIdx.x;

    const __hip_bfloat16* fsrc = feats + (size_t)uv * Bc * 64;
    #pragma unroll
    for (int i = 0; i < 8; i++) {
        int flat = i * 256 + t;
        int row = flat >> 6;
        int brow = b0 + row;
        if (brow >= Bc) brow = Bc - 1;
        sF[row][flat & 63] = b2f(fsrc[(size_t)brow * 64 + (flat & 63)]);
    }
    const size_t woff = (size_t)uv * 2 * 64 * 64;
    if (isbf) {
        const __hip_bfloat16* wsrc = (const __hip_bfloat16*)Wd + woff;
        #pragma unroll
        for (int i = 0; i < 32; i++) {
            int flat = i * 256 + t;
            ((float*)sW)[flat] = b2f(wsrc[flat]);
        }
    } else {
        const float* wsrc = (const float*)Wd + woff;
        #pragma unroll
        for (int i = 0; i < 32; i++) {
            int flat = i * 256 + t;
            ((float*)sW)[flat] = wsrc[flat];
        }
    }
    __syncthreads();

    #pragma unroll
    for (int i = 0; i < 16; i++) {
        int flat = i * 256 + t;
        int k = flat & 63;
        int r = (flat >> 6) & 1;
        int b = flat >> 7;
        if (b0 + b >= Bc) continue;
        float acc = 0.f;
        #pragma unroll 8
        for (int c = 0; c < 64; c++) acc = fmaf(sF[b][c], sW[r][c][k], acc);
        const int bg = b_off + b0 + b;
        const int ou = k >> 3, ov = k & 7;
        const size_t oidx = (((size_t)bg * 64 + (u * 8 + ou)) * 64 + (v * 8 + ov)) * 2 + r;
        if (isbf) ((__hip_bfloat16*)out)[oidx] = __float2bfloat16(acc);
        else      ((float*)out)[oidx] = acc;
    }
}

// ---------------------------------------------------------------------------
extern "C" void kernel_launch(void* const* d_in, const int* in_sizes, int n_in,
                              void* d_out, int out_size, void* d_ws, size_t ws_size,
                              hipStream_t stream)
{
    (void)in_sizes; (void)n_in; (void)out_size;

    const void* in_data = d_in[0];
    const void* filt    = d_in[1];
    const void* bias0   = d_in[2];
    const void* fl[7];
    const void* bl[7];
    for (int l = 1; l <= 6; l++) {
        fl[l] = d_in[1 + 2 * l];
        bl[l] = d_in[2 + 2 * l];
    }
    const void* Wd = d_in[15];

    const int Bfull = 128;
    const size_t perB = (size_t)64 * 64 * 64;   // elems per batch per buffer
    const size_t flagBytes = 256;

    const size_t avail = ws_size > flagBytes ? ws_size - flagBytes : 0;
    int Bc = 0;
    for (int c = 128; c >= 1; c >>= 1) {
        if ((size_t)2 * c * perB * sizeof(__hip_bfloat16) <= avail) { Bc = c; break; }
    }
    if (Bc == 0) return;

    int* flag = (int*)d_ws;
    __hip_bfloat16* bufA = (__hip_bfloat16*)((char*)d_ws + flagBytes);
    __hip_bfloat16* bufB = bufA + (size_t)Bc * perB;

    k_detect<<<dim3(1), 64, 0, stream>>>((const uint32_t*)in_data, flag);

    for (int b_off = 0; b_off < Bfull; b_off += Bc) {
        k_stage0<<<dim3(Bc * 64), 256, 0, stream>>>(in_data, filt, bias0, bufA, flag, b_off);

        __hip_bfloat16* cur = bufA;
        __hip_bfloat16* nxt = bufB;
        for (int lvl = 1; lvl <= 6; lvl++) {
            const int Nu = 1 << (lvl < 3 ? lvl : 3);
            const int H  = 64 >> lvl;
            const int rep = (lvl <= 3) ? 1 : 0;
            dim3 grid(Nu * Nu * H * H);
            k_level<<<grid, 256, 0, stream>>>(cur, fl[lvl], bl[lvl], nxt, flag, Nu, H, H, Bc, rep);
            __hip_bfloat16* tmp = cur; cur = nxt; nxt = tmp;
        }

        dim3 fgrid(64, (Bc >= 32) ? (Bc / 32) : 1);
        k_final<<<fgrid, 256, 0, stream>>>(cur, Wd, d_out, flag, Bc, b_off);
    }
}

// Round 4
// 292.911 us; speedup vs baseline: 3.7933x; 1.2262x over previous
//
#include <hip/hip_runtime.h>
#include <hip/hip_bf16.h>
#include <cstdint>
#include <cstddef>

// ButterflyLayer2D on MI355X.
// stage0 (VALU) -> 6 butterfly levels as bf16 MFMA GEMMs -> final VALU GEMM.
// Weights pre-transposed once into MFMA B-fragment layout (bf16) in d_ws;
// A and B staged via global_load_lds (width 16, conflict-free LDS writes);
// repeat levels (1-3) compute all 4 (u,v) children per block (wave = child)
// so parent input is fetched exactly once.

typedef __attribute__((ext_vector_type(8))) short short8;
typedef __attribute__((ext_vector_type(4))) float f32x4;
typedef unsigned short ushort_t;

static __device__ __forceinline__ float b2f(const __hip_bfloat16 x) {
    return __bfloat162float(x);
}
static __device__ __forceinline__ ushort_t f2bf(float x) {
    __hip_bfloat16 h = __float2bfloat16(x);
    ushort_t u;
    __builtin_memcpy(&u, &h, 2);
    return u;
}
static __device__ __forceinline__ void gl_lds16(const void* g, void* l) {
    __builtin_amdgcn_global_load_lds(
        (const __attribute__((address_space(1))) void*)g,
        (__attribute__((address_space(3))) void*)l, 16, 0, 0);
}

// ---------------------------------------------------------------------------
// Dtype detection (flag: 0 = f32, 1 = bf16) — verified rounds 2-3.
// ---------------------------------------------------------------------------
__global__ void k_detect(const uint32_t* __restrict__ in, int* __restrict__ flag) {
    const int t = threadIdx.x;  // 64 threads
    const float v = __uint_as_float(in[t]);
    const bool plaus = (v == 0.0f) || (fabsf(v) > 1e-8f && fabsf(v) < 1e4f);
    const unsigned long long m = __ballot(plaus);
    if (t == 0) *flag = (__popcll(m) >= 48) ? 0 : 1;
}

// ---------------------------------------------------------------------------
// Weight prep: convert level weights to bf16 in B-fragment-major layout.
// Dst octet gid: lane=gid&63, slot=(gid>>6)&7, sitetap=gid>>9 (per level).
// B-frag: slot=ks*4+nh; lane=(n&15)|(q<<4); elem j: k=ks*32+q*8+j, n=(lane&15)+nh*16.
// Src: f[site,tap,c=k,o=n] = fsrc[sitetap*4096 + k*64 + n].
// Octet counts per level: 8192, 32768, 131072 x4 (total 565248; grid 2208).
// ---------------------------------------------------------------------------
__global__ __launch_bounds__(256) void k_prepw(
    const void* f1, const void* f2, const void* f3,
    const void* f4, const void* f5, const void* f6,
    ushort_t* __restrict__ wbuf, const int* __restrict__ flag)
{
    const int isbf = *flag;
    const int gid = blockIdx.x * 256 + threadIdx.x;
    const void* fsrc; int base;
    if      (gid <   8192) { fsrc = f1; base = 0;      }
    else if (gid <  40960) { fsrc = f2; base = 8192;   }
    else if (gid < 172032) { fsrc = f3; base = 40960;  }
    else if (gid < 303104) { fsrc = f4; base = 172032; }
    else if (gid < 434176) { fsrc = f5; base = 303104; }
    else if (gid < 565248) { fsrc = f6; base = 434176; }
    else return;
    const int local = gid - base;
    const int lane = local & 63;
    const int slot = (local >> 6) & 7;
    const int sitetap = local >> 9;
    const int ks = slot >> 2, nh = slot & 3, q = lane >> 4;
    const int n = (lane & 15) + nh * 16;
    const int kbase = ks * 32 + q * 8;
    ushort_t pk[8];
    if (isbf) {
        const ushort_t* s = (const ushort_t*)fsrc + (size_t)sitetap * 4096;
        #pragma unroll
        for (int j = 0; j < 8; j++) pk[j] = s[(kbase + j) * 64 + n];
    } else {
        const float* s = (const float*)fsrc + (size_t)sitetap * 4096;
        #pragma unroll
        for (int j = 0; j < 8; j++) pk[j] = f2bf(s[(kbase + j) * 64 + n]);
    }
    *(uint4*)&wbuf[(size_t)gid * 8] = *(uint4*)pk;
}

// ---------------------------------------------------------------------------
// Bias prep -> f32. Sizes: 256,1024,4096x4 (total 17664; grid 69).
// ---------------------------------------------------------------------------
__global__ __launch_bounds__(256) void k_prepb(
    const void* b1, const void* b2, const void* b3,
    const void* b4, const void* b5, const void* b6,
    float* __restrict__ bbuf, const int* __restrict__ flag)
{
    const int isbf = *flag;
    const int gid = blockIdx.x * 256 + threadIdx.x;
    const void* src; int base;
    if      (gid <   256) { src = b1; base = 0;     }
    else if (gid <  1280) { src = b2; base = 256;   }
    else if (gid <  5376) { src = b3; base = 1280;  }
    else if (gid <  9472) { src = b4; base = 5376;  }
    else if (gid < 13568) { src = b5; base = 9472;  }
    else if (gid < 17664) { src = b6; base = 13568; }
    else return;
    const int local = gid - base;
    bbuf[gid] = isbf ? b2f(((const __hip_bfloat16*)src)[local])
                     : ((const float*)src)[local];
}

// ---------------------------------------------------------------------------
// Stage 0 (unchanged from round 3, passed): patch-embed, bf16 out.
// ---------------------------------------------------------------------------
__global__ __launch_bounds__(256) void k_stage0(
    const void* __restrict__ in_data, const void* __restrict__ filt,
    const void* __restrict__ bias, __hip_bfloat16* __restrict__ x0,
    const int* __restrict__ flag, int b_off)
{
    const int isbf = *flag;
    const int blk = blockIdx.x;
    const int X  = blk & 63;
    const int bl = blk >> 6;
    const int bg = bl + b_off;

    __shared__ float sIn[4][256];
    __shared__ float sF[16][64];
    __shared__ float sB[64];

    const int t = threadIdx.x;
    const size_t srow = ((size_t)bg * 256 + (size_t)X * 4) * 256;

    if (isbf) {
        const __hip_bfloat16* src = (const __hip_bfloat16*)in_data + srow;
        #pragma unroll
        for (int i = 0; i < 4; i++) {
            int flat = i * 256 + t;
            int p = flat >> 8, col = flat & 255;
            sIn[p][col] = b2f(src[(size_t)p * 256 + col]);
        }
        const __hip_bfloat16* fsrc = (const __hip_bfloat16*)filt;
        #pragma unroll
        for (int i = 0; i < 4; i++) {
            int flat = i * 256 + t;
            sF[flat >> 6][flat & 63] = b2f(fsrc[flat]);
        }
        if (t < 64) sB[t] = b2f(((const __hip_bfloat16*)bias)[t]);
    } else {
        const float* src = (const float*)in_data + srow;
        #pragma unroll
        for (int i = 0; i < 4; i++) {
            int flat = i * 256 + t;
            int p = flat >> 8, col = flat & 255;
            sIn[p][col] = src[(size_t)p * 256 + col];
        }
        const float* fsrc = (const float*)filt;
        #pragma unroll
        for (int i = 0; i < 4; i++) {
            int flat = i * 256 + t;
            sF[flat >> 6][flat & 63] = fsrc[flat];
        }
        if (t < 64) sB[t] = ((const float*)bias)[t];
    }
    __syncthreads();

    __hip_bfloat16* dst = x0 + ((size_t)bl * 64 + X) * 64 * 64;
    #pragma unroll
    for (int i = 0; i < 16; i++) {
        int flat = i * 256 + t;
        int c = flat & 63, Y = flat >> 6;
        float acc = sB[c];
        #pragma unroll
        for (int p = 0; p < 4; p++) {
            #pragma unroll
            for (int q = 0; q < 4; q++) {
                acc = fmaf(sIn[p][Y * 4 + q], sF[p * 4 + q][c], acc);
            }
        }
        dst[(size_t)Y * 64 + c] = __float2bfloat16(fmaxf(acc, 0.f));
    }
}

// ---------------------------------------------------------------------------
// Repeat level (1-3): block = (parent site, h, w, m-tile of 64), wave = child.
// Each wave: M=64 x N=64 GEMM for its (u,v) child; A shared across waves.
// grid.x = Nv_in^2 * HW^2 * mtiles.
// ---------------------------------------------------------------------------
__global__ __launch_bounds__(256) void k_level4(
    const __hip_bfloat16* __restrict__ xin,
    const ushort_t* __restrict__ wbuf,   // level-offset applied by host
    const float* __restrict__ bbuf,      // level-offset applied by host
    __hip_bfloat16* __restrict__ xout,
    int Nv_out, int HW, int Bc, int mtiles)
{
    __shared__ ushort_t smem[20480];     // A: 8*512 | B: 4 children * 8*512
    __shared__ float sBias[4][64];
    ushort_t* sA = smem;
    ushort_t* sB = smem + 4096;

    int idx = blockIdx.x;
    const int mt = idx % mtiles; idx /= mtiles;
    const int w  = idx % HW; idx /= HW;
    const int h  = idx % HW; idx /= HW;
    const int Nv_in = Nv_out >> 1;
    const int vp = idx % Nv_in;
    const int up = idx / Nv_in;

    const int t = threadIdx.x;
    const int wave = t >> 6, lane = t & 63;
    const int lm = lane & 15, lq = lane >> 4;

    {   // bias: thread t loads child (t>>6), channel (t&63)
        const int ct = t >> 6, o = t & 63;
        const int so_t = (2 * up + (ct >> 1)) * Nv_out + (2 * vp + (ct & 1));
        sBias[ct][o] = bbuf[so_t * 64 + o];
    }

    const int so = (2 * up + (wave >> 1)) * Nv_out + (2 * vp + (wave & 1));
    const int H_in = HW * 2;
    const size_t bstride = (size_t)H_in * H_in * 64;
    const size_t siteb = (size_t)(up * Nv_in + vp) * Bc * bstride;
    const ushort_t* wsite = wbuf + (size_t)so * 4 * 4096;

    const f32x4 zero = {0.f, 0.f, 0.f, 0.f};
    f32x4 acc[4][4];
    #pragma unroll
    for (int i = 0; i < 4; i++)
        #pragma unroll
        for (int j = 0; j < 4; j++) acc[i][j] = zero;

    for (int tap = 0; tap < 4; tap++) {
        const int hi = 2 * h + (tap >> 1), wi = 2 * w + (tap & 1);
        const size_t tapoff = siteb + ((size_t)hi * H_in + wi) * 64;
        // A: wave stages slots {2*wave, 2*wave+1} (8 slots total, M=64)
        #pragma unroll
        for (int s2 = 0; s2 < 2; s2++) {
            const int s = wave * 2 + s2;
            const int ks = s >> 2, mh = s & 3;
            int b = mt * 64 + lm + mh * 16;
            if (b >= Bc) b = Bc - 1;
            gl_lds16(xin + tapoff + (size_t)b * bstride + ks * 32 + lq * 8,
                     &sA[s * 512]);
        }
        // B: wave stages its own child's 8 slots (contiguous, pre-transposed)
        const ushort_t* wt = wsite + (size_t)tap * 4096;
        #pragma unroll
        for (int s = 0; s < 8; s++) {
            gl_lds16(wt + s * 512 + lane * 8, &sB[wave * 4096 + s * 512]);
        }
        __syncthreads();

        #pragma unroll
        for (int ks = 0; ks < 2; ks++) {
            short8 bf0 = *(const short8*)&sB[wave * 4096 + (ks * 4 + 0) * 512 + lane * 8];
            short8 bf1 = *(const short8*)&sB[wave * 4096 + (ks * 4 + 1) * 512 + lane * 8];
            short8 bf2 = *(const short8*)&sB[wave * 4096 + (ks * 4 + 2) * 512 + lane * 8];
            short8 bf3 = *(const short8*)&sB[wave * 4096 + (ks * 4 + 3) * 512 + lane * 8];
            #pragma unroll
            for (int fm = 0; fm < 4; fm++) {
                short8 a = *(const short8*)&sA[(ks * 4 + fm) * 512 + lane * 8];
                acc[fm][0] = __builtin_amdgcn_mfma_f32_16x16x32_bf16(a, bf0, acc[fm][0], 0, 0, 0);
                acc[fm][1] = __builtin_amdgcn_mfma_f32_16x16x32_bf16(a, bf1, acc[fm][1], 0, 0, 0);
                acc[fm][2] = __builtin_amdgcn_mfma_f32_16x16x32_bf16(a, bf2, acc[fm][2], 0, 0, 0);
                acc[fm][3] = __builtin_amdgcn_mfma_f32_16x16x32_bf16(a, bf3, acc[fm][3], 0, 0, 0);
            }
        }
        __syncthreads();
    }

    // epilogue: wave-local out-tile (64 rows x stride 68: disjoint bank sets)
    float bv[4];
    #pragma unroll
    for (int fn = 0; fn < 4; fn++) bv[fn] = sBias[wave][fn * 16 + lm];
    ushort_t* so_buf = smem + wave * 4352;
    #pragma unroll
    for (int fm = 0; fm < 4; fm++) {
        #pragma unroll
        for (int fn = 0; fn < 4; fn++) {
            #pragma unroll
            for (int r = 0; r < 4; r++) {
                const int row = fm * 16 + lq * 4 + r;
                so_buf[row * 68 + fn * 16 + lm] =
                    f2bf(fmaxf(acc[fm][fn][r] + bv[fn], 0.f));
            }
        }
    }
    __syncthreads();

    const size_t ostride = (size_t)HW * HW * 64;
    const size_t obase = (size_t)so * Bc * ostride + ((size_t)h * HW + w) * 64;
    #pragma unroll
    for (int i = 0; i < 8; i++) {
        const int task = i * 64 + lane;
        const int oct = task & 7, row = task >> 3;
        const int b = mt * 64 + row;
        if (b < Bc) {
            *(uint4*)(xout + obase + (size_t)b * ostride + oct * 8) =
                *(const uint4*)&so_buf[row * 68 + oct * 8];
        }
    }
}

// ---------------------------------------------------------------------------
// Non-repeat level (4-6): block = (site, h, w, m-tile of 128); waves split M.
// grid.x = Nv^2 * HW^2 * mtiles.
// ---------------------------------------------------------------------------
__global__ __launch_bounds__(256) void k_level1(
    const __hip_bfloat16* __restrict__ xin,
    const ushort_t* __restrict__ wbuf,
    const float* __restrict__ bbuf,
    __hip_bfloat16* __restrict__ xout,
    int Nv, int HW, int Bc, int mtiles)
{
    __shared__ ushort_t smem[12288];     // A: 16*512 | B: 8*512
    __shared__ float sBias[64];
    ushort_t* sA = smem;
    ushort_t* sB = smem + 8192;

    int idx = blockIdx.x;
    const int mt = idx % mtiles; idx /= mtiles;
    const int w  = idx % HW; idx /= HW;
    const int h  = idx % HW; idx /= HW;
    const int site = idx;                // u*Nv+v

    const int t = threadIdx.x;
    const int wave = t >> 6, lane = t & 63;
    const int lm = lane & 15, lq = lane >> 4;

    if (t < 64) sBias[t] = bbuf[site * 64 + t];

    const int H_in = HW * 2;
    const size_t bstride = (size_t)H_in * H_in * 64;
    const size_t siteb = (size_t)site * Bc * bstride;
    const ushort_t* wsite = wbuf + (size_t)site * 4 * 4096;

    const f32x4 zero = {0.f, 0.f, 0.f, 0.f};
    f32x4 acc[2][4];
    #pragma unroll
    for (int i = 0; i < 2; i++)
        #pragma unroll
        for (int j = 0; j < 4; j++) acc[i][j] = zero;

    for (int tap = 0; tap < 4; tap++) {
        const int hi = 2 * h + (tap >> 1), wi = 2 * w + (tap & 1);
        const size_t tapoff = siteb + ((size_t)hi * H_in + wi) * 64;
        // A: 16 slots (2 ks x 8 mh); wave stages 4
        #pragma unroll
        for (int s2 = 0; s2 < 4; s2++) {
            const int s = wave * 4 + s2;
            const int ks = s >> 3, mh = s & 7;
            int b = mt * 128 + lm + mh * 16;
            if (b >= Bc) b = Bc - 1;
            gl_lds16(xin + tapoff + (size_t)b * bstride + ks * 32 + lq * 8,
                     &sA[s * 512]);
        }
        // B: 8 slots shared; wave stages 2
        const ushort_t* wt = wsite + (size_t)tap * 4096;
        #pragma unroll
        for (int s2 = 0; s2 < 2; s2++) {
            const int s = wave * 2 + s2;
            gl_lds16(wt + s * 512 + lane * 8, &sB[s * 512]);
        }
        __syncthreads();

        #pragma unroll
        for (int ks = 0; ks < 2; ks++) {
            short8 bf0 = *(const short8*)&sB[(ks * 4 + 0) * 512 + lane * 8];
            short8 bf1 = *(const short8*)&sB[(ks * 4 + 1) * 512 + lane * 8];
            short8 bf2 = *(const short8*)&sB[(ks * 4 + 2) * 512 + lane * 8];
            short8 bf3 = *(const short8*)&sB[(ks * 4 + 3) * 512 + lane * 8];
            #pragma unroll
            for (int fml = 0; fml < 2; fml++) {
                short8 a = *(const short8*)&sA[(ks * 8 + wave * 2 + fml) * 512 + lane * 8];
                acc[fml][0] = __builtin_amdgcn_mfma_f32_16x16x32_bf16(a, bf0, acc[fml][0], 0, 0, 0);
                acc[fml][1] = __builtin_amdgcn_mfma_f32_16x16x32_bf16(a, bf1, acc[fml][1], 0, 0, 0);
                acc[fml][2] = __builtin_amdgcn_mfma_f32_16x16x32_bf16(a, bf2, acc[fml][2], 0, 0, 0);
                acc[fml][3] = __builtin_amdgcn_mfma_f32_16x16x32_bf16(a, bf3, acc[fml][3], 0, 0, 0);
            }
        }
        __syncthreads();
    }

    float bv[4];
    #pragma unroll
    for (int fn = 0; fn < 4; fn++) bv[fn] = sBias[fn * 16 + lm];
    ushort_t* so_buf = smem;             // 128 rows x stride 68 = 8704 <= 12288
    #pragma unroll
    for (int fml = 0; fml < 2; fml++) {
        #pragma unroll
        for (int fn = 0; fn < 4; fn++) {
            #pragma unroll
            for (int r = 0; r < 4; r++) {
                const int row = wave * 32 + fml * 16 + lq * 4 + r;
                so_buf[row * 68 + fn * 16 + lm] =
                    f2bf(fmaxf(acc[fml][fn][r] + bv[fn], 0.f));
            }
        }
    }
    __syncthreads();

    const size_t ostride = (size_t)HW * HW * 64;
    const size_t obase = (size_t)site * Bc * ostride + ((size_t)h * HW + w) * 64;
    #pragma unroll
    for (int i = 0; i < 4; i++) {
        const int task = i * 256 + t;
        const int oct = task & 7, row = task >> 3;
        const int b = mt * 128 + row;
        if (b < Bc) {
            *(uint4*)(xout + obase + (size_t)b * ostride + oct * 8) =
                *(const uint4*)&so_buf[row * 68 + oct * 8];
        }
    }
}

// ---------------------------------------------------------------------------
// Final (unchanged from round 3, passed).
// ---------------------------------------------------------------------------
__global__ __launch_bounds__(256) void k_final(
    const __hip_bfloat16* __restrict__ feats, const void* __restrict__ Wd,
    void* __restrict__ out, const int* __restrict__ flag, int Bc, int b_off)
{
    const int isbf = *flag;
    const int uv = blockIdx.x;
    const int u = uv >> 3, v = uv & 7;
    const int b0 = blockIdx.y * 32;

    __shared__ float sF[32][64];
    __shared__ float sW[2][64][64];

    const int t = threadIdx.x;

    const __hip_bfloat16* fsrc = feats + (size_t)uv * Bc * 64;
    #pragma unroll
    for (int i = 0; i < 8; i++) {
        int flat = i * 256 + t;
        int row = flat >> 6;
        int brow = b0 + row;
        if (brow >= Bc) brow = Bc - 1;
        sF[row][flat & 63] = b2f(fsrc[(size_t)brow * 64 + (flat & 63)]);
    }
    const size_t woff = (size_t)uv * 2 * 64 * 64;
    if (isbf) {
        const __hip_bfloat16* wsrc = (const __hip_bfloat16*)Wd + woff;
        #pragma unroll
        for (int i = 0; i < 32; i++) {
            int flat = i * 256 + t;
            ((float*)sW)[flat] = b2f(wsrc[flat]);
        }
    } else {
        const float* wsrc = (const float*)Wd + woff;
        #pragma unroll
        for (int i = 0; i < 32; i++) {
            int flat = i * 256 + t;
            ((float*)sW)[flat] = wsrc[flat];
        }
    }
    __syncthreads();

    #pragma unroll
    for (int i = 0; i < 16; i++) {
        int flat = i * 256 + t;
        int k = flat & 63;
        int r = (flat >> 6) & 1;
        int b = flat >> 7;
        if (b0 + b >= Bc) continue;
        float acc = 0.f;
        #pragma unroll 8
        for (int c = 0; c < 64; c++) acc = fmaf(sF[b][c], sW[r][c][k], acc);
        const int bg = b_off + b0 + b;
        const int ou = k >> 3, ov = k & 7;
        const size_t oidx = (((size_t)bg * 64 + (u * 8 + ou)) * 64 + (v * 8 + ov)) * 2 + r;
        if (isbf) ((__hip_bfloat16*)out)[oidx] = __float2bfloat16(acc);
        else      ((float*)out)[oidx] = acc;
    }
}

// ---------------------------------------------------------------------------
extern "C" void kernel_launch(void* const* d_in, const int* in_sizes, int n_in,
                              void* d_out, int out_size, void* d_ws, size_t ws_size,
                              hipStream_t stream)
{
    (void)in_sizes; (void)n_in; (void)out_size;

    const void* in_data = d_in[0];
    const void* filt    = d_in[1];
    const void* bias0   = d_in[2];
    const void* fl[7];
    const void* bl[7];
    for (int l = 1; l <= 6; l++) {
        fl[l] = d_in[1 + 2 * l];
        bl[l] = d_in[2 + 2 * l];
    }
    const void* Wd = d_in[15];

    const int Bfull = 128;
    const size_t perB = (size_t)64 * 64 * 64;      // elems per batch per buffer

    // ws layout: [flag 256B][wbuf 9043968B][bbuf 70656B][bufA][bufB]
    const size_t wbufBytes = 4521984ull * 2;       // 565248 octets * 16B
    const size_t bbufBytes = 17664ull * 4;
    const size_t headBytes = 256 + wbufBytes + bbufBytes;  // = 9114880 (256-aligned)

    const size_t avail = ws_size > headBytes ? ws_size - headBytes : 0;
    int Bc = 0;
    for (int c = 128; c >= 1; c >>= 1) {
        if ((size_t)2 * c * perB * sizeof(__hip_bfloat16) <= avail) { Bc = c; break; }
    }
    if (Bc == 0) return;

    int* flag = (int*)d_ws;
    ushort_t* wbuf = (ushort_t*)((char*)d_ws + 256);
    float* bbuf = (float*)((char*)d_ws + 256 + wbufBytes);
    __hip_bfloat16* bufA = (__hip_bfloat16*)((char*)d_ws + headBytes);
    __hip_bfloat16* bufB = bufA + (size_t)Bc * perB;

    // level offsets into wbuf (bf16 elems) and bbuf (f32 elems)
    static const size_t w_off[7] = {0, 0, 65536, 327680, 1376256, 2424832, 3473408};
    static const int    b_off_tab[7] = {0, 0, 256, 1280, 5376, 9472, 13568};

    k_detect<<<dim3(1), 64, 0, stream>>>((const uint32_t*)in_data, flag);
    k_prepw<<<dim3(2208), 256, 0, stream>>>(fl[1], fl[2], fl[3], fl[4], fl[5], fl[6], wbuf, flag);
    k_prepb<<<dim3(69), 256, 0, stream>>>(bl[1], bl[2], bl[3], bl[4], bl[5], bl[6], bbuf, flag);

    const int mt4 = (Bc + 63) / 64;
    const int mt1 = (Bc + 127) / 128;

    for (int b_off = 0; b_off < Bfull; b_off += Bc) {
        k_stage0<<<dim3(Bc * 64), 256, 0, stream>>>(in_data, filt, bias0, bufA, flag, b_off);

        __hip_bfloat16* cur = bufA;
        __hip_bfloat16* nxt = bufB;
        for (int lvl = 1; lvl <= 6; lvl++) {
            const int Nu = 1 << (lvl < 3 ? lvl : 3);
            const int H  = 64 >> lvl;
            if (lvl <= 3) {
                const int Nv_in = Nu >> 1;
                dim3 grid(Nv_in * Nv_in * H * H * mt4);
                k_level4<<<grid, 256, 0, stream>>>(cur, wbuf + w_off[lvl],
                    bbuf + b_off_tab[lvl], nxt, Nu, H, Bc, mt4);
            } else {
                dim3 grid(Nu * Nu * H * H * mt1);
                k_level1<<<grid, 256, 0, stream>>>(cur, wbuf + w_off[lvl],
                    bbuf + b_off_tab[lvl], nxt, Nu, H, Bc, mt1);
            }
            __hip_bfloat16* tmp = cur; cur = nxt; nxt = tmp;
        }

        dim3 fgrid(64, (Bc >= 32) ? (Bc / 32) : 1);
        k_final<<<fgrid, 256, 0, stream>>>(cur, Wd, d_out, flag, Bc, b_off);
    }
}

// Round 5
// 266.638 us; speedup vs baseline: 4.1670x; 1.0985x over previous
//
#include <hip/hip_runtime.h>
#include <hip/hip_bf16.h>
#include <cstdint>
#include <cstddef>

// ButterflyLayer2D on MI355X.
// stage0 (VALU, register-tiled) -> levels 1-5 as bf16 MFMA GEMMs ->
// k_tail = fused level-6 GEMM + final projection (Wd pre-transposed).
// Weights pre-transposed once into MFMA B-fragment layout (bf16) in d_ws;
// A and B staged via global_load_lds (width 16, conflict-free LDS writes);
// repeat levels (1-3) compute all 4 (u,v) children per block (wave = child).

typedef __attribute__((ext_vector_type(8))) short short8;
typedef __attribute__((ext_vector_type(4))) float f32x4;
typedef unsigned short ushort_t;

static __device__ __forceinline__ float b2f(const __hip_bfloat16 x) {
    return __bfloat162float(x);
}
static __device__ __forceinline__ ushort_t f2bf(float x) {
    __hip_bfloat16 h = __float2bfloat16(x);
    ushort_t u;
    __builtin_memcpy(&u, &h, 2);
    return u;
}
static __device__ __forceinline__ void gl_lds16(const void* g, void* l) {
    __builtin_amdgcn_global_load_lds(
        (const __attribute__((address_space(1))) void*)g,
        (__attribute__((address_space(3))) void*)l, 16, 0, 0);
}

// ---------------------------------------------------------------------------
// Dtype detection (flag: 0 = f32, 1 = bf16) — verified rounds 2-4.
// ---------------------------------------------------------------------------
__global__ void k_detect(const uint32_t* __restrict__ in, int* __restrict__ flag) {
    const int t = threadIdx.x;  // 64 threads
    const float v = __uint_as_float(in[t]);
    const bool plaus = (v == 0.0f) || (fabsf(v) > 1e-8f && fabsf(v) < 1e4f);
    const unsigned long long m = __ballot(plaus);
    if (t == 0) *flag = (__popcll(m) >= 48) ? 0 : 1;
}

// ---------------------------------------------------------------------------
// Weight prep: level weights -> bf16 B-fragment layout; plus Wd -> B-frag.
// Level octets (gid < 565248): lane=gid&63, slot=(gid>>6)&7, sitetap=gid>>9.
//   B-frag: slot=ks*4+nh; elem j: k=ks*32+(lane>>4)*8+j, n=(lane&15)+nh*16.
// Wd octets (gid in [565248, 630784)): local: lane&63, slot=(l>>6)&15, site=l>>10.
//   slot=ks2*8+nh (N=128, K=64): n=nh*16+(lane&15) -> r=n>>6, kk=n&63;
//   c=ks2*32+(lane>>4)*8+j; src Wd[((site*2+r)*64+c)*64+kk].
// ---------------------------------------------------------------------------
__global__ __launch_bounds__(256) void k_prepw(
    const void* f1, const void* f2, const void* f3,
    const void* f4, const void* f5, const void* f6, const void* wdsrc,
    ushort_t* __restrict__ wbuf, ushort_t* __restrict__ wdbuf,
    const int* __restrict__ flag)
{
    const int isbf = *flag;
    const int gid = blockIdx.x * 256 + threadIdx.x;
    if (gid >= 630784) return;
    if (gid >= 565248) {
        const int local = gid - 565248;
        const int lane = local & 63;
        const int slot = (local >> 6) & 15;
        const int site = local >> 10;
        const int ks2 = slot >> 3, nh = slot & 7, q = lane >> 4;
        const int n = nh * 16 + (lane & 15);
        const int r = n >> 6, kk = n & 63;
        const int cbase = ks2 * 32 + q * 8;
        ushort_t pk[8];
        if (isbf) {
            const ushort_t* s = (const ushort_t*)wdsrc;
            #pragma unroll
            for (int j = 0; j < 8; j++)
                pk[j] = s[(((size_t)(site * 2 + r) * 64 + cbase + j) * 64) + kk];
        } else {
            const float* s = (const float*)wdsrc;
            #pragma unroll
            for (int j = 0; j < 8; j++)
                pk[j] = f2bf(s[(((size_t)(site * 2 + r) * 64 + cbase + j) * 64) + kk]);
        }
        *(uint4*)&wdbuf[(size_t)local * 8] = *(uint4*)pk;
        return;
    }
    const void* fsrc; int base;
    if      (gid <   8192) { fsrc = f1; base = 0;      }
    else if (gid <  40960) { fsrc = f2; base = 8192;   }
    else if (gid < 172032) { fsrc = f3; base = 40960;  }
    else if (gid < 303104) { fsrc = f4; base = 172032; }
    else if (gid < 434176) { fsrc = f5; base = 303104; }
    else                   { fsrc = f6; base = 434176; }
    const int local = gid - base;
    const int lane = local & 63;
    const int slot = (local >> 6) & 7;
    const int sitetap = local >> 9;
    const int ks = slot >> 2, nh = slot & 3, q = lane >> 4;
    const int n = (lane & 15) + nh * 16;
    const int kbase = ks * 32 + q * 8;
    ushort_t pk[8];
    if (isbf) {
        const ushort_t* s = (const ushort_t*)fsrc + (size_t)sitetap * 4096;
        #pragma unroll
        for (int j = 0; j < 8; j++) pk[j] = s[(kbase + j) * 64 + n];
    } else {
        const float* s = (const float*)fsrc + (size_t)sitetap * 4096;
        #pragma unroll
        for (int j = 0; j < 8; j++) pk[j] = f2bf(s[(kbase + j) * 64 + n]);
    }
    *(uint4*)&wbuf[(size_t)gid * 8] = *(uint4*)pk;
}

// ---------------------------------------------------------------------------
// Bias prep -> f32. Sizes: 256,1024,4096x4 (total 17664; grid 69).
// ---------------------------------------------------------------------------
__global__ __launch_bounds__(256) void k_prepb(
    const void* b1, const void* b2, const void* b3,
    const void* b4, const void* b5, const void* b6,
    float* __restrict__ bbuf, const int* __restrict__ flag)
{
    const int isbf = *flag;
    const int gid = blockIdx.x * 256 + threadIdx.x;
    const void* src; int base;
    if      (gid <   256) { src = b1; base = 0;     }
    else if (gid <  1280) { src = b2; base = 256;   }
    else if (gid <  5376) { src = b3; base = 1280;  }
    else if (gid <  9472) { src = b4; base = 5376;  }
    else if (gid < 13568) { src = b5; base = 9472;  }
    else if (gid < 17664) { src = b6; base = 13568; }
    else return;
    const int local = gid - base;
    bbuf[gid] = isbf ? b2f(((const __hip_bfloat16*)src)[local])
                     : ((const float*)src)[local];
}

// ---------------------------------------------------------------------------
// Stage 0, register-tiled: thread = 4Y x 4c tile. LDS reads all b128,
// <=2-way patterns. grid.x = Bc*64, 256 threads.
// ---------------------------------------------------------------------------
__global__ __launch_bounds__(256) void k_stage0(
    const void* __restrict__ in_data, const void* __restrict__ filt,
    const void* __restrict__ bias, __hip_bfloat16* __restrict__ x0,
    const int* __restrict__ flag, int b_off)
{
    const int isbf = *flag;
    const int blk = blockIdx.x;
    const int X  = blk & 63;
    const int bl = blk >> 6;
    const int bg = bl + b_off;

    __shared__ float sIn[4][256];
    __shared__ float sF[16][64];
    __shared__ float sB[64];

    const int t = threadIdx.x;
    const size_t srow = ((size_t)bg * 256 + (size_t)X * 4) * 256;

    if (isbf) {
        const __hip_bfloat16* src = (const __hip_bfloat16*)in_data + srow;
        #pragma unroll
        for (int i = 0; i < 4; i++) {
            int flat = i * 256 + t;
            int p = flat >> 8, col = flat & 255;
            sIn[p][col] = b2f(src[(size_t)p * 256 + col]);
        }
        const __hip_bfloat16* fsrc = (const __hip_bfloat16*)filt;
        #pragma unroll
        for (int i = 0; i < 4; i++) {
            int flat = i * 256 + t;
            sF[flat >> 6][flat & 63] = b2f(fsrc[flat]);
        }
        if (t < 64) sB[t] = b2f(((const __hip_bfloat16*)bias)[t]);
    } else {
        const float* src = (const float*)in_data + srow;
        const int p = t >> 6, c4 = (t & 63) * 4;
        *(float4*)&sIn[p][c4] = *(const float4*)(src + (size_t)p * 256 + c4);
        const float* fsrc = (const float*)filt;
        #pragma unroll
        for (int i = 0; i < 4; i++) {
            int flat = i * 256 + t;
            sF[flat >> 6][flat & 63] = fsrc[flat];
        }
        if (t < 64) sB[t] = ((const float*)bias)[t];
    }
    __syncthreads();

    const int ty = t >> 4;          // Y-group: Y = ty*4 + yi
    const int tc = t & 15;          // c-group: c = tc*4 + ci

    float acc[4][4];
    {
        const float4 bv = *(const float4*)&sB[tc * 4];
        #pragma unroll
        for (int yi = 0; yi < 4; yi++) {
            acc[yi][0] = bv.x; acc[yi][1] = bv.y;
            acc[yi][2] = bv.z; acc[yi][3] = bv.w;
        }
    }

    #pragma unroll
    for (int p = 0; p < 4; p++) {
        float4 rin[4], rf[4];
        #pragma unroll
        for (int yi = 0; yi < 4; yi++)
            rin[yi] = *(const float4*)&sIn[p][ty * 16 + yi * 4];
        #pragma unroll
        for (int q = 0; q < 4; q++)
            rf[q] = *(const float4*)&sF[p * 4 + q][tc * 4];
        #pragma unroll
        for (int yi = 0; yi < 4; yi++) {
            #pragma unroll
            for (int q = 0; q < 4; q++) {
                const float a = ((const float*)&rin[yi])[q];
                acc[yi][0] = fmaf(a, rf[q].x, acc[yi][0]);
                acc[yi][1] = fmaf(a, rf[q].y, acc[yi][1]);
                acc[yi][2] = fmaf(a, rf[q].z, acc[yi][2]);
                acc[yi][3] = fmaf(a, rf[q].w, acc[yi][3]);
            }
        }
    }

    ushort_t* dst = (ushort_t*)(x0 + ((size_t)bl * 64 + X) * 64 * 64);
    #pragma unroll
    for (int yi = 0; yi < 4; yi++) {
        uint2 pk;
        pk.x = (uint32_t)f2bf(fmaxf(acc[yi][0], 0.f))
             | ((uint32_t)f2bf(fmaxf(acc[yi][1], 0.f)) << 16);
        pk.y = (uint32_t)f2bf(fmaxf(acc[yi][2], 0.f))
             | ((uint32_t)f2bf(fmaxf(acc[yi][3], 0.f)) << 16);
        *(uint2*)(dst + (size_t)(ty * 4 + yi) * 64 + tc * 4) = pk;
    }
}

// ---------------------------------------------------------------------------
// Repeat level (1-3): block = (parent site, h, w, m-tile of 64), wave = child.
// ---------------------------------------------------------------------------
__global__ __launch_bounds__(256) void k_level4(
    const __hip_bfloat16* __restrict__ xin,
    const ushort_t* __restrict__ wbuf,   // level-offset applied by host
    const float* __restrict__ bbuf,      // level-offset applied by host
    __hip_bfloat16* __restrict__ xout,
    int Nv_out, int HW, int Bc, int mtiles)
{
    __shared__ ushort_t smem[20480];     // A: 8*512 | B: 4 children * 8*512
    __shared__ float sBias[4][64];
    ushort_t* sA = smem;
    ushort_t* sB = smem + 4096;

    int idx = blockIdx.x;
    const int mt = idx % mtiles; idx /= mtiles;
    const int w  = idx % HW; idx /= HW;
    const int h  = idx % HW; idx /= HW;
    const int Nv_in = Nv_out >> 1;
    const int vp = idx % Nv_in;
    const int up = idx / Nv_in;

    const int t = threadIdx.x;
    const int wave = t >> 6, lane = t & 63;
    const int lm = lane & 15, lq = lane >> 4;

    {
        const int ct = t >> 6, o = t & 63;
        const int so_t = (2 * up + (ct >> 1)) * Nv_out + (2 * vp + (ct & 1));
        sBias[ct][o] = bbuf[so_t * 64 + o];
    }

    const int so = (2 * up + (wave >> 1)) * Nv_out + (2 * vp + (wave & 1));
    const int H_in = HW * 2;
    const size_t bstride = (size_t)H_in * H_in * 64;
    const size_t siteb = (size_t)(up * Nv_in + vp) * Bc * bstride;
    const ushort_t* wsite = wbuf + (size_t)so * 4 * 4096;

    const f32x4 zero = {0.f, 0.f, 0.f, 0.f};
    f32x4 acc[4][4];
    #pragma unroll
    for (int i = 0; i < 4; i++)
        #pragma unroll
        for (int j = 0; j < 4; j++) acc[i][j] = zero;

    for (int tap = 0; tap < 4; tap++) {
        const int hi = 2 * h + (tap >> 1), wi = 2 * w + (tap & 1);
        const size_t tapoff = siteb + ((size_t)hi * H_in + wi) * 64;
        #pragma unroll
        for (int s2 = 0; s2 < 2; s2++) {
            const int s = wave * 2 + s2;
            const int ks = s >> 2, mh = s & 3;
            int b = mt * 64 + lm + mh * 16;
            if (b >= Bc) b = Bc - 1;
            gl_lds16(xin + tapoff + (size_t)b * bstride + ks * 32 + lq * 8,
                     &sA[s * 512]);
        }
        const ushort_t* wt = wsite + (size_t)tap * 4096;
        #pragma unroll
        for (int s = 0; s < 8; s++) {
            gl_lds16(wt + s * 512 + lane * 8, &sB[wave * 4096 + s * 512]);
        }
        __syncthreads();

        #pragma unroll
        for (int ks = 0; ks < 2; ks++) {
            short8 bf0 = *(const short8*)&sB[wave * 4096 + (ks * 4 + 0) * 512 + lane * 8];
            short8 bf1 = *(const short8*)&sB[wave * 4096 + (ks * 4 + 1) * 512 + lane * 8];
            short8 bf2 = *(const short8*)&sB[wave * 4096 + (ks * 4 + 2) * 512 + lane * 8];
            short8 bf3 = *(const short8*)&sB[wave * 4096 + (ks * 4 + 3) * 512 + lane * 8];
            #pragma unroll
            for (int fm = 0; fm < 4; fm++) {
                short8 a = *(const short8*)&sA[(ks * 4 + fm) * 512 + lane * 8];
                acc[fm][0] = __builtin_amdgcn_mfma_f32_16x16x32_bf16(a, bf0, acc[fm][0], 0, 0, 0);
                acc[fm][1] = __builtin_amdgcn_mfma_f32_16x16x32_bf16(a, bf1, acc[fm][1], 0, 0, 0);
                acc[fm][2] = __builtin_amdgcn_mfma_f32_16x16x32_bf16(a, bf2, acc[fm][2], 0, 0, 0);
                acc[fm][3] = __builtin_amdgcn_mfma_f32_16x16x32_bf16(a, bf3, acc[fm][3], 0, 0, 0);
            }
        }
        __syncthreads();
    }

    float bv[4];
    #pragma unroll
    for (int fn = 0; fn < 4; fn++) bv[fn] = sBias[wave][fn * 16 + lm];
    ushort_t* so_buf = smem + wave * 4352;
    #pragma unroll
    for (int fm = 0; fm < 4; fm++) {
        #pragma unroll
        for (int fn = 0; fn < 4; fn++) {
            #pragma unroll
            for (int r = 0; r < 4; r++) {
                const int row = fm * 16 + lq * 4 + r;
                so_buf[row * 68 + fn * 16 + lm] =
                    f2bf(fmaxf(acc[fm][fn][r] + bv[fn], 0.f));
            }
        }
    }
    __syncthreads();

    const size_t ostride = (size_t)HW * HW * 64;
    const size_t obase = (size_t)so * Bc * ostride + ((size_t)h * HW + w) * 64;
    #pragma unroll
    for (int i = 0; i < 8; i++) {
        const int task = i * 64 + lane;
        const int oct = task & 7, row = task >> 3;
        const int b = mt * 64 + row;
        if (b < Bc) {
            *(uint4*)(xout + obase + (size_t)b * ostride + oct * 8) =
                *(const uint4*)&so_buf[row * 68 + oct * 8];
        }
    }
}

// ---------------------------------------------------------------------------
// Non-repeat level (4-5): block = (site, h, w, m-tile of 128); waves split M.
// ---------------------------------------------------------------------------
__global__ __launch_bounds__(256) void k_level1(
    const __hip_bfloat16* __restrict__ xin,
    const ushort_t* __restrict__ wbuf,
    const float* __restrict__ bbuf,
    __hip_bfloat16* __restrict__ xout,
    int Nv, int HW, int Bc, int mtiles)
{
    __shared__ ushort_t smem[12288];     // A: 16*512 | B: 8*512
    __shared__ float sBias[64];
    ushort_t* sA = smem;
    ushort_t* sB = smem + 8192;

    int idx = blockIdx.x;
    const int mt = idx % mtiles; idx /= mtiles;
    const int w  = idx % HW; idx /= HW;
    const int h  = idx % HW; idx /= HW;
    const int site = idx;                // u*Nv+v

    const int t = threadIdx.x;
    const int wave = t >> 6, lane = t & 63;
    const int lm = lane & 15, lq = lane >> 4;

    if (t < 64) sBias[t] = bbuf[site * 64 + t];

    const int H_in = HW * 2;
    const size_t bstride = (size_t)H_in * H_in * 64;
    const size_t siteb = (size_t)site * Bc * bstride;
    const ushort_t* wsite = wbuf + (size_t)site * 4 * 4096;

    const f32x4 zero = {0.f, 0.f, 0.f, 0.f};
    f32x4 acc[2][4];
    #pragma unroll
    for (int i = 0; i < 2; i++)
        #pragma unroll
        for (int j = 0; j < 4; j++) acc[i][j] = zero;

    for (int tap = 0; tap < 4; tap++) {
        const int hi = 2 * h + (tap >> 1), wi = 2 * w + (tap & 1);
        const size_t tapoff = siteb + ((size_t)hi * H_in + wi) * 64;
        #pragma unroll
        for (int s2 = 0; s2 < 4; s2++) {
            const int s = wave * 4 + s2;
            const int ks = s >> 3, mh = s & 7;
            int b = mt * 128 + lm + mh * 16;
            if (b >= Bc) b = Bc - 1;
            gl_lds16(xin + tapoff + (size_t)b * bstride + ks * 32 + lq * 8,
                     &sA[s * 512]);
        }
        const ushort_t* wt = wsite + (size_t)tap * 4096;
        #pragma unroll
        for (int s2 = 0; s2 < 2; s2++) {
            const int s = wave * 2 + s2;
            gl_lds16(wt + s * 512 + lane * 8, &sB[s * 512]);
        }
        __syncthreads();

        #pragma unroll
        for (int ks = 0; ks < 2; ks++) {
            short8 bf0 = *(const short8*)&sB[(ks * 4 + 0) * 512 + lane * 8];
            short8 bf1 = *(const short8*)&sB[(ks * 4 + 1) * 512 + lane * 8];
            short8 bf2 = *(const short8*)&sB[(ks * 4 + 2) * 512 + lane * 8];
            short8 bf3 = *(const short8*)&sB[(ks * 4 + 3) * 512 + lane * 8];
            #pragma unroll
            for (int fml = 0; fml < 2; fml++) {
                short8 a = *(const short8*)&sA[(ks * 8 + wave * 2 + fml) * 512 + lane * 8];
                acc[fml][0] = __builtin_amdgcn_mfma_f32_16x16x32_bf16(a, bf0, acc[fml][0], 0, 0, 0);
                acc[fml][1] = __builtin_amdgcn_mfma_f32_16x16x32_bf16(a, bf1, acc[fml][1], 0, 0, 0);
                acc[fml][2] = __builtin_amdgcn_mfma_f32_16x16x32_bf16(a, bf2, acc[fml][2], 0, 0, 0);
                acc[fml][3] = __builtin_amdgcn_mfma_f32_16x16x32_bf16(a, bf3, acc[fml][3], 0, 0, 0);
            }
        }
        __syncthreads();
    }

    float bv[4];
    #pragma unroll
    for (int fn = 0; fn < 4; fn++) bv[fn] = sBias[fn * 16 + lm];
    ushort_t* so_buf = smem;             // 128 rows x stride 68 = 8704
    #pragma unroll
    for (int fml = 0; fml < 2; fml++) {
        #pragma unroll
        for (int fn = 0; fn < 4; fn++) {
            #pragma unroll
            for (int r = 0; r < 4; r++) {
                const int row = wave * 32 + fml * 16 + lq * 4 + r;
                so_buf[row * 68 + fn * 16 + lm] =
                    f2bf(fmaxf(acc[fml][fn][r] + bv[fn], 0.f));
            }
        }
    }
    __syncthreads();

    const size_t ostride = (size_t)HW * HW * 64;
    const size_t obase = (size_t)site * Bc * ostride + ((size_t)h * HW + w) * 64;
    #pragma unroll
    for (int i = 0; i < 4; i++) {
        const int task = i * 256 + t;
        const int oct = task & 7, row = task >> 3;
        const int b = mt * 128 + row;
        if (b < Bc) {
            *(uint4*)(xout + obase + (size_t)b * ostride + oct * 8) =
                *(const uint4*)&so_buf[row * 68 + oct * 8];
        }
    }
}

// ---------------------------------------------------------------------------
// k_tail: fused level 6 + final projection. One block per site (64 blocks).
// Phase 1: L6 GEMM M=128,K=256(contig per b-row),N=64 -> bias/relu ->
//          bf16 feats in LDS (row stride 72).
// Phase 2: final GEMM M=128,K=64,N=128 (n=r*64+ou*8+ov), Wd pre-transposed.
// ---------------------------------------------------------------------------
__global__ __launch_bounds__(256) void k_tail(
    const __hip_bfloat16* __restrict__ xin,   // (64, Bc, 2,2,64) = site,b,256
    const ushort_t* __restrict__ w6,          // wbuf + level-6 offset
    const float* __restrict__ b6,             // bbuf + level-6 offset
    const ushort_t* __restrict__ wd,          // wdbuf
    void* __restrict__ out,                   // (128,64,64,2)
    const int* __restrict__ flag, int Bc, int b_off)
{
    const int isbf = *flag;
    const int site = blockIdx.x;              // u*8+v
    const int u = site >> 3, v = site & 7;

    __shared__ ushort_t sA[16 * 512];         // phase1 A-chunk; phase2 B2
    __shared__ ushort_t sB1[8 * 512];
    __shared__ ushort_t sMid[128 * 72];       // feats, bf16
    __shared__ float sBias[64];

    const int t = threadIdx.x;
    const int wave = t >> 6, lane = t & 63;
    const int lm = lane & 15, lq = lane >> 4;

    if (t < 64) sBias[t] = b6[site * 64 + t];

    const f32x4 zero = {0.f, 0.f, 0.f, 0.f};
    f32x4 acc1[2][4];
    #pragma unroll
    for (int i = 0; i < 2; i++)
        #pragma unroll
        for (int j = 0; j < 4; j++) acc1[i][j] = zero;

    const size_t abase = (size_t)site * Bc * 256;

    for (int chunk = 0; chunk < 4; chunk++) {
        #pragma unroll
        for (int s2 = 0; s2 < 4; s2++) {
            const int s = wave * 4 + s2;
            const int ks = s >> 3, mh = s & 7;
            int b = mh * 16 + lm;
            if (b >= Bc) b = Bc - 1;
            gl_lds16(xin + abase + (size_t)b * 256 + chunk * 64 + ks * 32 + lq * 8,
                     &sA[s * 512]);
        }
        const ushort_t* wt = w6 + (size_t)(site * 4 + chunk) * 4096;
        #pragma unroll
        for (int s2 = 0; s2 < 2; s2++) {
            const int s = wave * 2 + s2;
            gl_lds16(wt + s * 512 + lane * 8, &sB1[s * 512]);
        }
        __syncthreads();

        #pragma unroll
        for (int ks = 0; ks < 2; ks++) {
            short8 bf0 = *(const short8*)&sB1[(ks * 4 + 0) * 512 + lane * 8];
            short8 bf1 = *(const short8*)&sB1[(ks * 4 + 1) * 512 + lane * 8];
            short8 bf2 = *(const short8*)&sB1[(ks * 4 + 2) * 512 + lane * 8];
            short8 bf3 = *(const short8*)&sB1[(ks * 4 + 3) * 512 + lane * 8];
            #pragma unroll
            for (int fml = 0; fml < 2; fml++) {
                short8 a = *(const short8*)&sA[(ks * 8 + wave * 2 + fml) * 512 + lane * 8];
                acc1[fml][0] = __builtin_amdgcn_mfma_f32_16x16x32_bf16(a, bf0, acc1[fml][0], 0, 0, 0);
                acc1[fml][1] = __builtin_amdgcn_mfma_f32_16x16x32_bf16(a, bf1, acc1[fml][1], 0, 0, 0);
                acc1[fml][2] = __builtin_amdgcn_mfma_f32_16x16x32_bf16(a, bf2, acc1[fml][2], 0, 0, 0);
                acc1[fml][3] = __builtin_amdgcn_mfma_f32_16x16x32_bf16(a, bf3, acc1[fml][3], 0, 0, 0);
            }
        }
        __syncthreads();
    }

    // epilogue 1: bias + relu -> sMid (feats, bf16, row stride 72)
    float bv[4];
    #pragma unroll
    for (int fn = 0; fn < 4; fn++) bv[fn] = sBias[fn * 16 + lm];
    #pragma unroll
    for (int fml = 0; fml < 2; fml++) {
        #pragma unroll
        for (int fn = 0; fn < 4; fn++) {
            #pragma unroll
            for (int r = 0; r < 4; r++) {
                const int row = wave * 32 + fml * 16 + lq * 4 + r;
                sMid[row * 72 + fn * 16 + lm] =
                    f2bf(fmaxf(acc1[fml][fn][r] + bv[fn], 0.f));
            }
        }
    }
    // stage B2 (Wd frags) into sA region (16 slots); overlaps epilogue stores
    #pragma unroll
    for (int s2 = 0; s2 < 4; s2++) {
        const int s = wave * 4 + s2;
        gl_lds16(wd + ((size_t)(site * 16 + s) * 64 + lane) * 8, &sA[s * 512]);
    }
    __syncthreads();

    // phase 2: M=128, K=64, N=128
    f32x4 acc2[2][8];
    #pragma unroll
    for (int i = 0; i < 2; i++)
        #pragma unroll
        for (int j = 0; j < 8; j++) acc2[i][j] = zero;

    #pragma unroll
    for (int ks2 = 0; ks2 < 2; ks2++) {
        short8 a20 = *(const short8*)&sMid[((wave * 2 + 0) * 16 + lm) * 72 + ks2 * 32 + lq * 8];
        short8 a21 = *(const short8*)&sMid[((wave * 2 + 1) * 16 + lm) * 72 + ks2 * 32 + lq * 8];
        #pragma unroll
        for (int nh = 0; nh < 8; nh++) {
            short8 bv2 = *(const short8*)&sA[(ks2 * 8 + nh) * 512 + lane * 8];
            acc2[0][nh] = __builtin_amdgcn_mfma_f32_16x16x32_bf16(a20, bv2, acc2[0][nh], 0, 0, 0);
            acc2[1][nh] = __builtin_amdgcn_mfma_f32_16x16x32_bf16(a21, bv2, acc2[1][nh], 0, 0, 0);
        }
    }

    // epilogue 2: scatter-store to out
    #pragma unroll
    for (int fml = 0; fml < 2; fml++) {
        #pragma unroll
        for (int nh = 0; nh < 8; nh++) {
            const int n = nh * 16 + lm;
            const int r = n >> 6, ou = (n >> 3) & 7, ov = n & 7;
            const size_t obase =
                (((size_t)0 * 64 + (u * 8 + ou)) * 64 + (v * 8 + ov)) * 2 + r;
            #pragma unroll
            for (int reg = 0; reg < 4; reg++) {
                const int brow = wave * 32 + fml * 16 + lq * 4 + reg;
                if (brow < Bc) {
                    const size_t oidx = obase + (size_t)(b_off + brow) * 8192;
                    if (isbf) ((__hip_bfloat16*)out)[oidx] =
                        __float2bfloat16(acc2[fml][nh][reg]);
                    else ((float*)out)[oidx] = acc2[fml][nh][reg];
                }
            }
        }
    }
}

// ---------------------------------------------------------------------------
extern "C" void kernel_launch(void* const* d_in, const int* in_sizes, int n_in,
                              void* d_out, int out_size, void* d_ws, size_t ws_size,
                              hipStream_t stream)
{
    (void)in_sizes; (void)n_in; (void)out_size;

    const void* in_data = d_in[0];
    const void* filt    = d_in[1];
    const void* bias0   = d_in[2];
    const void* fl[7];
    const void* bl[7];
    for (int l = 1; l <= 6; l++) {
        fl[l] = d_in[1 + 2 * l];
        bl[l] = d_in[2 + 2 * l];
    }
    const void* Wd = d_in[15];

    const int Bfull = 128;
    const size_t perB = (size_t)64 * 64 * 64;      // elems per batch per buffer

    // ws: [flag 256B][wbuf 9043968B][wdbuf 1048576B][bbuf 70656B][bufA][bufB]
    const size_t wbufBytes  = 565248ull * 16;
    const size_t wdbufBytes = 65536ull * 16;
    const size_t bbufBytes  = 17664ull * 4;
    const size_t headBytes  = 256 + wbufBytes + wdbufBytes + bbufBytes;

    const size_t avail = ws_size > headBytes ? ws_size - headBytes : 0;
    int Bc = 0;
    for (int c = 128; c >= 1; c >>= 1) {
        if ((size_t)2 * c * perB * sizeof(__hip_bfloat16) <= avail) { Bc = c; break; }
    }
    if (Bc == 0) return;

    int* flag = (int*)d_ws;
    ushort_t* wbuf  = (ushort_t*)((char*)d_ws + 256);
    ushort_t* wdbuf = (ushort_t*)((char*)d_ws + 256 + wbufBytes);
    float* bbuf = (float*)((char*)d_ws + 256 + wbufBytes + wdbufBytes);
    __hip_bfloat16* bufA = (__hip_bfloat16*)((char*)d_ws + headBytes);
    __hip_bfloat16* bufB = bufA + (size_t)Bc * perB;

    // level offsets into wbuf (bf16 elems) and bbuf (f32 elems)
    static const size_t w_off[7] = {0, 0, 65536, 327680, 1376256, 2424832, 3473408};
    static const int    b_off_tab[7] = {0, 0, 256, 1280, 5376, 9472, 13568};

    k_detect<<<dim3(1), 64, 0, stream>>>((const uint32_t*)in_data, flag);
    k_prepw<<<dim3(2464), 256, 0, stream>>>(fl[1], fl[2], fl[3], fl[4], fl[5], fl[6],
                                            Wd, wbuf, wdbuf, flag);
    k_prepb<<<dim3(69), 256, 0, stream>>>(bl[1], bl[2], bl[3], bl[4], bl[5], bl[6], bbuf, flag);

    const int mt4 = (Bc + 63) / 64;
    const int mt1 = (Bc + 127) / 128;

    for (int b_off = 0; b_off < Bfull; b_off += Bc) {
        k_stage0<<<dim3(Bc * 64), 256, 0, stream>>>(in_data, filt, bias0, bufA, flag, b_off);

        __hip_bfloat16* cur = bufA;
        __hip_bfloat16* nxt = bufB;
        for (int lvl = 1; lvl <= 5; lvl++) {
            const int Nu = 1 << (lvl < 3 ? lvl : 3);
            const int H  = 64 >> lvl;
            if (lvl <= 3) {
                const int Nv_in = Nu >> 1;
                dim3 grid(Nv_in * Nv_in * H * H * mt4);
                k_level4<<<grid, 256, 0, stream>>>(cur, wbuf + w_off[lvl],
                    bbuf + b_off_tab[lvl], nxt, Nu, H, Bc, mt4);
            } else {
                dim3 grid(Nu * Nu * H * H * mt1);
                k_level1<<<grid, 256, 0, stream>>>(cur, wbuf + w_off[lvl],
                    bbuf + b_off_tab[lvl], nxt, Nu, H, Bc, mt1);
            }
            __hip_bfloat16* tmp = cur; cur = nxt; nxt = tmp;
        }

        k_tail<<<dim3(64), 256, 0, stream>>>(cur, wbuf + w_off[6],
            bbuf + b_off_tab[6], wdbuf, d_out, flag, Bc, b_off);
    }
}

// Round 6
// 248.829 us; speedup vs baseline: 4.4653x; 1.0716x over previous
//
#include <hip/hip_runtime.h>
#include <hip/hip_bf16.h>
#include <cstdint>
#include <cstddef>

// ButterflyLayer2D on MI355X.
// stage0 (VALU, register-tiled) -> levels 1-3 as bf16 MFMA GEMMs (4-children
// A-sharing) -> k_f456 = fused L4+L5+L6+final (one block per site x 32-batch,
// wave-private A staging, 4 barriers total).
// Weights pre-transposed once into MFMA B-fragment layout (bf16) in d_ws.

typedef __attribute__((ext_vector_type(8))) short short8;
typedef __attribute__((ext_vector_type(4))) float f32x4;
typedef unsigned short ushort_t;

static __device__ __forceinline__ float b2f(const __hip_bfloat16 x) {
    return __bfloat162float(x);
}
static __device__ __forceinline__ ushort_t f2bf(float x) {
    __hip_bfloat16 h = __float2bfloat16(x);
    ushort_t u;
    __builtin_memcpy(&u, &h, 2);
    return u;
}
static __device__ __forceinline__ void gl_lds16(const void* g, void* l) {
    __builtin_amdgcn_global_load_lds(
        (const __attribute__((address_space(1))) void*)g,
        (__attribute__((address_space(3))) void*)l, 16, 0, 0);
}
// gfx9 waitcnt encodings: lgkmcnt(0) only / vmcnt(0) only
#define WAIT_LGKM0() __builtin_amdgcn_s_waitcnt(0xC07F)
#define WAIT_VM0()   __builtin_amdgcn_s_waitcnt(0x0F70)

// ---------------------------------------------------------------------------
// k_prep: merged dtype-detect + weight transpose + bias convert.
// Every block self-detects dtype from in_data[0..63] (f32 words plausible vs
// bf16-pair words implausible); block 0 publishes flag for later kernels.
// gid ranges: [0,565248) level weights; [565248,630784) Wd; [630784,648448) bias.
// ---------------------------------------------------------------------------
__global__ __launch_bounds__(256) void k_prep(
    const uint32_t* __restrict__ in_words,
    const void* f1, const void* f2, const void* f3,
    const void* f4, const void* f5, const void* f6, const void* wdsrc,
    const void* b1, const void* b2, const void* b3,
    const void* b4, const void* b5, const void* b6,
    ushort_t* __restrict__ wbuf, ushort_t* __restrict__ wdbuf,
    float* __restrict__ bbuf, int* __restrict__ flag)
{
    __shared__ int sflag;
    const int t = threadIdx.x;
    if (t < 64) {
        const float v = __uint_as_float(in_words[t]);
        const bool plaus = (v == 0.0f) || (fabsf(v) > 1e-8f && fabsf(v) < 1e4f);
        const unsigned long long m = __ballot(plaus);
        if (t == 0) sflag = (__popcll(m) >= 48) ? 0 : 1;
    }
    __syncthreads();
    const int isbf = sflag;
    const int gid = blockIdx.x * 256 + t;
    if (blockIdx.x == 0 && t == 0) *flag = isbf;

    if (gid >= 648448) return;
    if (gid >= 630784) {
        // biases -> f32
        const int bg = gid - 630784;
        const void* src; int base;
        if      (bg <   256) { src = b1; base = 0;     }
        else if (bg <  1280) { src = b2; base = 256;   }
        else if (bg <  5376) { src = b3; base = 1280;  }
        else if (bg <  9472) { src = b4; base = 5376;  }
        else if (bg < 13568) { src = b5; base = 9472;  }
        else                 { src = b6; base = 13568; }
        const int local = bg - base;
        bbuf[bg] = isbf ? b2f(((const __hip_bfloat16*)src)[local])
                        : ((const float*)src)[local];
        return;
    }
    if (gid >= 565248) {
        // Wd -> B-frag (N=128 over (r,ou,ov), K=64 over c)
        const int local = gid - 565248;
        const int lane = local & 63;
        const int slot = (local >> 6) & 15;
        const int site = local >> 10;
        const int ks2 = slot >> 3, nh = slot & 7, q = lane >> 4;
        const int n = nh * 16 + (lane & 15);
        const int r = n >> 6, kk = n & 63;
        const int cbase = ks2 * 32 + q * 8;
        ushort_t pk[8];
        if (isbf) {
            const ushort_t* s = (const ushort_t*)wdsrc;
            #pragma unroll
            for (int j = 0; j < 8; j++)
                pk[j] = s[(((size_t)(site * 2 + r) * 64 + cbase + j) * 64) + kk];
        } else {
            const float* s = (const float*)wdsrc;
            #pragma unroll
            for (int j = 0; j < 8; j++)
                pk[j] = f2bf(s[(((size_t)(site * 2 + r) * 64 + cbase + j) * 64) + kk]);
        }
        *(uint4*)&wdbuf[(size_t)local * 8] = *(uint4*)pk;
        return;
    }
    // level weights -> B-frag (per (site,tap): 8 slots, K=64, N=64)
    const void* fsrc; int base;
    if      (gid <   8192) { fsrc = f1; base = 0;      }
    else if (gid <  40960) { fsrc = f2; base = 8192;   }
    else if (gid < 172032) { fsrc = f3; base = 40960;  }
    else if (gid < 303104) { fsrc = f4; base = 172032; }
    else if (gid < 434176) { fsrc = f5; base = 303104; }
    else                   { fsrc = f6; base = 434176; }
    const int local = gid - base;
    const int lane = local & 63;
    const int slot = (local >> 6) & 7;
    const int sitetap = local >> 9;
    const int ks = slot >> 2, nh = slot & 3, q = lane >> 4;
    const int n = (lane & 15) + nh * 16;
    const int kbase = ks * 32 + q * 8;
    ushort_t pk[8];
    if (isbf) {
        const ushort_t* s = (const ushort_t*)fsrc + (size_t)sitetap * 4096;
        #pragma unroll
        for (int j = 0; j < 8; j++) pk[j] = s[(kbase + j) * 64 + n];
    } else {
        const float* s = (const float*)fsrc + (size_t)sitetap * 4096;
        #pragma unroll
        for (int j = 0; j < 8; j++) pk[j] = f2bf(s[(kbase + j) * 64 + n]);
    }
    *(uint4*)&wbuf[(size_t)gid * 8] = *(uint4*)pk;
}

// ---------------------------------------------------------------------------
// Stage 0 (verified round 5): patch-embed, register-tiled, bf16 out.
// ---------------------------------------------------------------------------
__global__ __launch_bounds__(256) void k_stage0(
    const void* __restrict__ in_data, const void* __restrict__ filt,
    const void* __restrict__ bias, __hip_bfloat16* __restrict__ x0,
    const int* __restrict__ flag, int b_off)
{
    const int isbf = *flag;
    const int blk = blockIdx.x;
    const int X  = blk & 63;
    const int bl = blk >> 6;
    const int bg = bl + b_off;

    __shared__ float sIn[4][256];
    __shared__ float sF[16][64];
    __shared__ float sB[64];

    const int t = threadIdx.x;
    const size_t srow = ((size_t)bg * 256 + (size_t)X * 4) * 256;

    if (isbf) {
        const __hip_bfloat16* src = (const __hip_bfloat16*)in_data + srow;
        #pragma unroll
        for (int i = 0; i < 4; i++) {
            int flat = i * 256 + t;
            int p = flat >> 8, col = flat & 255;
            sIn[p][col] = b2f(src[(size_t)p * 256 + col]);
        }
        const __hip_bfloat16* fsrc = (const __hip_bfloat16*)filt;
        #pragma unroll
        for (int i = 0; i < 4; i++) {
            int flat = i * 256 + t;
            sF[flat >> 6][flat & 63] = b2f(fsrc[flat]);
        }
        if (t < 64) sB[t] = b2f(((const __hip_bfloat16*)bias)[t]);
    } else {
        const float* src = (const float*)in_data + srow;
        const int p = t >> 6, c4 = (t & 63) * 4;
        *(float4*)&sIn[p][c4] = *(const float4*)(src + (size_t)p * 256 + c4);
        const float* fsrc = (const float*)filt;
        #pragma unroll
        for (int i = 0; i < 4; i++) {
            int flat = i * 256 + t;
            sF[flat >> 6][flat & 63] = fsrc[flat];
        }
        if (t < 64) sB[t] = ((const float*)bias)[t];
    }
    __syncthreads();

    const int ty = t >> 4;
    const int tc = t & 15;

    float acc[4][4];
    {
        const float4 bv = *(const float4*)&sB[tc * 4];
        #pragma unroll
        for (int yi = 0; yi < 4; yi++) {
            acc[yi][0] = bv.x; acc[yi][1] = bv.y;
            acc[yi][2] = bv.z; acc[yi][3] = bv.w;
        }
    }

    #pragma unroll
    for (int p = 0; p < 4; p++) {
        float4 rin[4], rf[4];
        #pragma unroll
        for (int yi = 0; yi < 4; yi++)
            rin[yi] = *(const float4*)&sIn[p][ty * 16 + yi * 4];
        #pragma unroll
        for (int q = 0; q < 4; q++)
            rf[q] = *(const float4*)&sF[p * 4 + q][tc * 4];
        #pragma unroll
        for (int yi = 0; yi < 4; yi++) {
            #pragma unroll
            for (int q = 0; q < 4; q++) {
                const float a = ((const float*)&rin[yi])[q];
                acc[yi][0] = fmaf(a, rf[q].x, acc[yi][0]);
                acc[yi][1] = fmaf(a, rf[q].y, acc[yi][1]);
                acc[yi][2] = fmaf(a, rf[q].z, acc[yi][2]);
                acc[yi][3] = fmaf(a, rf[q].w, acc[yi][3]);
            }
        }
    }

    ushort_t* dst = (ushort_t*)(x0 + ((size_t)bl * 64 + X) * 64 * 64);
    #pragma unroll
    for (int yi = 0; yi < 4; yi++) {
        uint2 pk;
        pk.x = (uint32_t)f2bf(fmaxf(acc[yi][0], 0.f))
             | ((uint32_t)f2bf(fmaxf(acc[yi][1], 0.f)) << 16);
        pk.y = (uint32_t)f2bf(fmaxf(acc[yi][2], 0.f))
             | ((uint32_t)f2bf(fmaxf(acc[yi][3], 0.f)) << 16);
        *(uint2*)(dst + (size_t)(ty * 4 + yi) * 64 + tc * 4) = pk;
    }
}

// ---------------------------------------------------------------------------
// Repeat level (1-3), verified rounds 4-5: block = (parent site, h, w, mtile
// of 64), wave = child; A fetched once for the 4 children.
// ---------------------------------------------------------------------------
__global__ __launch_bounds__(256) void k_level4(
    const __hip_bfloat16* __restrict__ xin,
    const ushort_t* __restrict__ wbuf,
    const float* __restrict__ bbuf,
    __hip_bfloat16* __restrict__ xout,
    int Nv_out, int HW, int Bc, int mtiles)
{
    __shared__ ushort_t smem[20480];
    __shared__ float sBias[4][64];
    ushort_t* sA = smem;
    ushort_t* sB = smem + 4096;

    int idx = blockIdx.x;
    const int mt = idx % mtiles; idx /= mtiles;
    const int w  = idx % HW; idx /= HW;
    const int h  = idx % HW; idx /= HW;
    const int Nv_in = Nv_out >> 1;
    const int vp = idx % Nv_in;
    const int up = idx / Nv_in;

    const int t = threadIdx.x;
    const int wave = t >> 6, lane = t & 63;
    const int lm = lane & 15, lq = lane >> 4;

    {
        const int ct = t >> 6, o = t & 63;
        const int so_t = (2 * up + (ct >> 1)) * Nv_out + (2 * vp + (ct & 1));
        sBias[ct][o] = bbuf[so_t * 64 + o];
    }

    const int so = (2 * up + (wave >> 1)) * Nv_out + (2 * vp + (wave & 1));
    const int H_in = HW * 2;
    const size_t bstride = (size_t)H_in * H_in * 64;
    const size_t siteb = (size_t)(up * Nv_in + vp) * Bc * bstride;
    const ushort_t* wsite = wbuf + (size_t)so * 4 * 4096;

    const f32x4 zero = {0.f, 0.f, 0.f, 0.f};
    f32x4 acc[4][4];
    #pragma unroll
    for (int i = 0; i < 4; i++)
        #pragma unroll
        for (int j = 0; j < 4; j++) acc[i][j] = zero;

    for (int tap = 0; tap < 4; tap++) {
        const int hi = 2 * h + (tap >> 1), wi = 2 * w + (tap & 1);
        const size_t tapoff = siteb + ((size_t)hi * H_in + wi) * 64;
        #pragma unroll
        for (int s2 = 0; s2 < 2; s2++) {
            const int s = wave * 2 + s2;
            const int ks = s >> 2, mh = s & 3;
            int b = mt * 64 + lm + mh * 16;
            if (b >= Bc) b = Bc - 1;
            gl_lds16(xin + tapoff + (size_t)b * bstride + ks * 32 + lq * 8,
                     &sA[s * 512]);
        }
        const ushort_t* wt = wsite + (size_t)tap * 4096;
        #pragma unroll
        for (int s = 0; s < 8; s++) {
            gl_lds16(wt + s * 512 + lane * 8, &sB[wave * 4096 + s * 512]);
        }
        __syncthreads();

        #pragma unroll
        for (int ks = 0; ks < 2; ks++) {
            short8 bf0 = *(const short8*)&sB[wave * 4096 + (ks * 4 + 0) * 512 + lane * 8];
            short8 bf1 = *(const short8*)&sB[wave * 4096 + (ks * 4 + 1) * 512 + lane * 8];
            short8 bf2 = *(const short8*)&sB[wave * 4096 + (ks * 4 + 2) * 512 + lane * 8];
            short8 bf3 = *(const short8*)&sB[wave * 4096 + (ks * 4 + 3) * 512 + lane * 8];
            #pragma unroll
            for (int fm = 0; fm < 4; fm++) {
                short8 a = *(const short8*)&sA[(ks * 4 + fm) * 512 + lane * 8];
                acc[fm][0] = __builtin_amdgcn_mfma_f32_16x16x32_bf16(a, bf0, acc[fm][0], 0, 0, 0);
                acc[fm][1] = __builtin_amdgcn_mfma_f32_16x16x32_bf16(a, bf1, acc[fm][1], 0, 0, 0);
                acc[fm][2] = __builtin_amdgcn_mfma_f32_16x16x32_bf16(a, bf2, acc[fm][2], 0, 0, 0);
                acc[fm][3] = __builtin_amdgcn_mfma_f32_16x16x32_bf16(a, bf3, acc[fm][3], 0, 0, 0);
            }
        }
        __syncthreads();
    }

    float bv[4];
    #pragma unroll
    for (int fn = 0; fn < 4; fn++) bv[fn] = sBias[wave][fn * 16 + lm];
    ushort_t* so_buf = smem + wave * 4352;
    #pragma unroll
    for (int fm = 0; fm < 4; fm++) {
        #pragma unroll
        for (int fn = 0; fn < 4; fn++) {
            #pragma unroll
            for (int r = 0; r < 4; r++) {
                const int row = fm * 16 + lq * 4 + r;
                so_buf[row * 68 + fn * 16 + lm] =
                    f2bf(fmaxf(acc[fm][fn][r] + bv[fn], 0.f));
            }
        }
    }
    __syncthreads();

    const size_t ostride = (size_t)HW * HW * 64;
    const size_t obase = (size_t)so * Bc * ostride + ((size_t)h * HW + w) * 64;
    #pragma unroll
    for (int i = 0; i < 8; i++) {
        const int task = i * 64 + lane;
        const int oct = task & 7, row = task >> 3;
        const int b = mt * 64 + row;
        if (b < Bc) {
            *(uint4*)(xout + obase + (size_t)b * ostride + oct * 8) =
                *(const uint4*)&so_buf[row * 68 + oct * 8];
        }
    }
}

// ---------------------------------------------------------------------------
// k_f456: fused L4 + L5 + L6 + final. Block = (site s in 64, 32-batch mtile).
// Grid = 64*mtiles (256 at Bc=128) -> 1 block/CU, ~150 KB LDS.
// Wave wv = (h5,w5) quadrant:
//   phase 1 (L4): 4 positions p4 = (2h5+a,2w5+b), A staged wave-private
//     (no barriers), acc over 4 taps (K=256), bias4+relu -> mid1 (wave-
//     private, row-major stride 264, k = i*64+ch).
//   phase 2 (L5): K=256 over mid1, B2 resident; bias5+relu -> mid2 slice
//     (stride 72) carved into own mid1 region. Still barrier-free.
//   barrier; stage B3 (L6 w) + B4 (Wd) over B1/B2; barrier.
//   phase 3 (L6): K=256 over the 4 mid2 slices, waves split N; bias6+relu
//     -> mid3 (stride 72, over dead A region); barrier.
//   phase 4 (final): M=32,K=64,N=128; scatter-store to out.
// ---------------------------------------------------------------------------
__global__ __launch_bounds__(256, 1) void k_f456(
    const __hip_bfloat16* __restrict__ xin,   // L3 out: (64, Bc, 8,8,64)
    const ushort_t* __restrict__ w4, const ushort_t* __restrict__ w5,
    const ushort_t* __restrict__ w6, const ushort_t* __restrict__ wd,
    const float* __restrict__ b4, const float* __restrict__ b5,
    const float* __restrict__ b6,
    void* __restrict__ out, const int* __restrict__ flag,
    int Bc, int b_off, int mtiles)
{
    const int isbf = *flag;
    const int bx = blockIdx.x;
    const int mt = bx % mtiles;
    const int site = bx / mtiles;
    const int u = site >> 3, v = site & 7;

    // ushort offsets: RB [0,32768) ; mid1 [32768, 32768+4*8448) ; A [66560, +8192)
    __shared__ ushort_t smem[74752];
    __shared__ float sBias[192];

    const int t = threadIdx.x;
    const int wv = t >> 6, lane = t & 63;
    const int lm = lane & 15, lq = lane >> 4;

    if (t < 64) {
        sBias[t]       = b4[site * 64 + t];
        sBias[64 + t]  = b5[site * 64 + t];
        sBias[128 + t] = b6[site * 64 + t];
    }

    // stage B1 (L4 weights, 32 slots) and B2 (L5 weights, 32 slots)
    {
        const ushort_t* w4s = w4 + (size_t)site * 16384;
        const ushort_t* w5s = w5 + (size_t)site * 16384;
        #pragma unroll
        for (int s2 = 0; s2 < 8; s2++) {
            const int s = wv * 8 + s2;
            gl_lds16(w4s + s * 512 + lane * 8, &smem[s * 512]);
            gl_lds16(w5s + s * 512 + lane * 8, &smem[16384 + s * 512]);
        }
    }
    __syncthreads();  // barrier A (drains vmcnt)

    const f32x4 zero = {0.f, 0.f, 0.f, 0.f};
    const int h5 = wv >> 1, w5p = wv & 1;
    ushort_t* mid1w = smem + 32768 + wv * 8448;
    ushort_t* Aw = smem + 66560 + wv * 2048;
    const size_t sb = (size_t)site * Bc;

    // ---------------- phase 1: L4 ----------------
    for (int i = 0; i < 4; i++) {
        const int h4 = 2 * h5 + (i >> 1), w4p = 2 * w5p + (i & 1);
        f32x4 acc[2][4];
        #pragma unroll
        for (int a_ = 0; a_ < 2; a_++)
            #pragma unroll
            for (int b_ = 0; b_ < 4; b_++) acc[a_][b_] = zero;

        for (int tap = 0; tap < 4; tap++) {
            const int h3 = 2 * h4 + (tap >> 1), w3 = 2 * w4p + (tap & 1);
            WAIT_LGKM0();  // prior ds_reads of Aw complete (WAR)
            #pragma unroll
            for (int sl = 0; sl < 4; sl++) {      // sl = ks*2+mh
                const int ks = sl >> 1, mh = sl & 1;
                int b = mt * 32 + mh * 16 + lm;
                if (b >= Bc) b = Bc - 1;
                gl_lds16(xin + (sb + b) * 4096 + (h3 * 8 + w3) * 64 + ks * 32 + lq * 8,
                         &Aw[sl * 512]);
            }
            WAIT_VM0();    // staged A visible
            #pragma unroll
            for (int ks = 0; ks < 2; ks++) {
                #pragma unroll
                for (int fm = 0; fm < 2; fm++) {
                    short8 a = *(const short8*)&Aw[(ks * 2 + fm) * 512 + lane * 8];
                    #pragma unroll
                    for (int fn = 0; fn < 4; fn++) {
                        short8 bfr = *(const short8*)&smem[(tap * 8 + ks * 4 + fn) * 512 + lane * 8];
                        acc[fm][fn] = __builtin_amdgcn_mfma_f32_16x16x32_bf16(a, bfr, acc[fm][fn], 0, 0, 0);
                    }
                }
            }
        }
        // epilogue -> mid1 (k = i*64 + ch), bias4 + relu
        #pragma unroll
        for (int fm = 0; fm < 2; fm++) {
            #pragma unroll
            for (int fn = 0; fn < 4; fn++) {
                #pragma unroll
                for (int r = 0; r < 4; r++) {
                    const int m = fm * 16 + lq * 4 + r;
                    const int ch = fn * 16 + lm;
                    mid1w[m * 264 + i * 64 + ch] =
                        f2bf(fmaxf(acc[fm][fn][r] + sBias[ch], 0.f));
                }
            }
        }
    }

    // ---------------- phase 2: L5 (barrier-free, mid1 wave-private) --------
    {
        f32x4 acc2[2][4];
        #pragma unroll
        for (int a_ = 0; a_ < 2; a_++)
            #pragma unroll
            for (int b_ = 0; b_ < 4; b_++) acc2[a_][b_] = zero;

        #pragma unroll
        for (int i = 0; i < 4; i++) {
            #pragma unroll
            for (int ks = 0; ks < 2; ks++) {
                short8 a0 = *(const short8*)&mid1w[lm * 264 + i * 64 + ks * 32 + lq * 8];
                short8 a1 = *(const short8*)&mid1w[(16 + lm) * 264 + i * 64 + ks * 32 + lq * 8];
                #pragma unroll
                for (int fn = 0; fn < 4; fn++) {
                    short8 bfr = *(const short8*)&smem[16384 + (i * 8 + ks * 4 + fn) * 512 + lane * 8];
                    acc2[0][fn] = __builtin_amdgcn_mfma_f32_16x16x32_bf16(a0, bfr, acc2[0][fn], 0, 0, 0);
                    acc2[1][fn] = __builtin_amdgcn_mfma_f32_16x16x32_bf16(a1, bfr, acc2[1][fn], 0, 0, 0);
                }
            }
        }
        // epilogue -> mid2 slice (stride 72) at own region base, bias5 + relu
        #pragma unroll
        for (int fm = 0; fm < 2; fm++) {
            #pragma unroll
            for (int fn = 0; fn < 4; fn++) {
                #pragma unroll
                for (int r = 0; r < 4; r++) {
                    const int m = fm * 16 + lq * 4 + r;
                    const int ch = fn * 16 + lm;
                    mid1w[m * 72 + ch] =
                        f2bf(fmaxf(acc2[fm][fn][r] + sBias[64 + ch], 0.f));
                }
            }
        }
    }
    __syncthreads();  // barrier B: mid2 visible; B1/B2 dead

    // stage B3 (L6 weights, 32 slots @RB[0]) and B4 (Wd, 16 slots @RB[16384])
    {
        const ushort_t* w6s = w6 + (size_t)site * 16384;
        const ushort_t* wds = wd + (size_t)site * 8192;
        #pragma unroll
        for (int s2 = 0; s2 < 8; s2++) {
            const int s = wv * 8 + s2;
            gl_lds16(w6s + s * 512 + lane * 8, &smem[s * 512]);
        }
        #pragma unroll
        for (int s2 = 0; s2 < 4; s2++) {
            const int s = wv * 4 + s2;
            gl_lds16(wds + s * 512 + lane * 8, &smem[16384 + s * 512]);
        }
    }
    __syncthreads();  // barrier C

    // ---------------- phase 3: L6, waves split N (nf = wv) ----------------
    {
        f32x4 acc3[2];
        acc3[0] = zero; acc3[1] = zero;
        #pragma unroll
        for (int tap = 0; tap < 4; tap++) {
            const ushort_t* sl = smem + 32768 + tap * 8448;  // mid2 slice
            #pragma unroll
            for (int ks = 0; ks < 2; ks++) {
                short8 a0 = *(const short8*)&sl[lm * 72 + ks * 32 + lq * 8];
                short8 a1 = *(const short8*)&sl[(16 + lm) * 72 + ks * 32 + lq * 8];
                short8 bfr = *(const short8*)&smem[(tap * 8 + ks * 4 + wv) * 512 + lane * 8];
                acc3[0] = __builtin_amdgcn_mfma_f32_16x16x32_bf16(a0, bfr, acc3[0], 0, 0, 0);
                acc3[1] = __builtin_amdgcn_mfma_f32_16x16x32_bf16(a1, bfr, acc3[1], 0, 0, 0);
            }
        }
        // epilogue -> mid3 (stride 72, over dead A region), bias6 + relu
        ushort_t* mid3 = smem + 66560;
        #pragma unroll
        for (int fm = 0; fm < 2; fm++) {
            #pragma unroll
            for (int r = 0; r < 4; r++) {
                const int m = fm * 16 + lq * 4 + r;
                const int ch = wv * 16 + lm;
                mid3[m * 72 + ch] =
                    f2bf(fmaxf(acc3[fm][r] + sBias[128 + ch], 0.f));
            }
        }
    }
    __syncthreads();  // barrier D

    // ---------------- phase 4: final projection ----------------
    {
        const ushort_t* mid3 = smem + 66560;
        f32x4 acc4[2][2];
        acc4[0][0] = zero; acc4[0][1] = zero; acc4[1][0] = zero; acc4[1][1] = zero;
        #pragma unroll
        for (int ks = 0; ks < 2; ks++) {
            short8 a0 = *(const short8*)&mid3[lm * 72 + ks * 32 + lq * 8];
            short8 a1 = *(const short8*)&mid3[(16 + lm) * 72 + ks * 32 + lq * 8];
            #pragma unroll
            for (int n2 = 0; n2 < 2; n2++) {
                const int nh = 2 * wv + n2;
                short8 bfr = *(const short8*)&smem[16384 + (ks * 8 + nh) * 512 + lane * 8];
                acc4[0][n2] = __builtin_amdgcn_mfma_f32_16x16x32_bf16(a0, bfr, acc4[0][n2], 0, 0, 0);
                acc4[1][n2] = __builtin_amdgcn_mfma_f32_16x16x32_bf16(a1, bfr, acc4[1][n2], 0, 0, 0);
            }
        }
        // scatter-store: n = nh*16+lm -> (r, ou, ov); row -> batch
        #pragma unroll
        for (int fm = 0; fm < 2; fm++) {
            #pragma unroll
            for (int n2 = 0; n2 < 2; n2++) {
                const int n = (2 * wv + n2) * 16 + lm;
                const int rr = n >> 6, ou = (n >> 3) & 7, ov = n & 7;
                const size_t obase =
                    (((size_t)(u * 8 + ou)) * 64 + (v * 8 + ov)) * 2 + rr;
                #pragma unroll
                for (int reg = 0; reg < 4; reg++) {
                    const int brow = mt * 32 + fm * 16 + lq * 4 + reg;
                    if (brow < Bc) {
                        const size_t oidx = obase + (size_t)(b_off + brow) * 8192;
                        if (isbf) ((__hip_bfloat16*)out)[oidx] =
                            __float2bfloat16(acc4[fm][n2][reg]);
                        else ((float*)out)[oidx] = acc4[fm][n2][reg];
                    }
                }
            }
        }
    }
}

// ---------------------------------------------------------------------------
extern "C" void kernel_launch(void* const* d_in, const int* in_sizes, int n_in,
                              void* d_out, int out_size, void* d_ws, size_t ws_size,
                              hipStream_t stream)
{
    (void)in_sizes; (void)n_in; (void)out_size;

    const void* in_data = d_in[0];
    const void* filt    = d_in[1];
    const void* bias0   = d_in[2];
    const void* fl[7];
    const void* bl[7];
    for (int l = 1; l <= 6; l++) {
        fl[l] = d_in[1 + 2 * l];
        bl[l] = d_in[2 + 2 * l];
    }
    const void* Wd = d_in[15];

    const int Bfull = 128;
    const size_t perB = (size_t)64 * 64 * 64;

    const size_t wbufBytes  = 565248ull * 16;
    const size_t wdbufBytes = 65536ull * 16;
    const size_t bbufBytes  = 17664ull * 4;
    const size_t headBytes  = 256 + wbufBytes + wdbufBytes + bbufBytes;

    const size_t avail = ws_size > headBytes ? ws_size - headBytes : 0;
    int Bc = 0;
    for (int c = 128; c >= 1; c >>= 1) {
        if ((size_t)2 * c * perB * sizeof(__hip_bfloat16) <= avail) { Bc = c; break; }
    }
    if (Bc == 0) return;

    int* flag = (int*)d_ws;
    ushort_t* wbuf  = (ushort_t*)((char*)d_ws + 256);
    ushort_t* wdbuf = (ushort_t*)((char*)d_ws + 256 + wbufBytes);
    float* bbuf = (float*)((char*)d_ws + 256 + wbufBytes + wdbufBytes);
    __hip_bfloat16* bufA = (__hip_bfloat16*)((char*)d_ws + headBytes);
    __hip_bfloat16* bufB = bufA + (size_t)Bc * perB;

    static const size_t w_off[7] = {0, 0, 65536, 327680, 1376256, 2424832, 3473408};
    static const int    b_off_tab[7] = {0, 0, 256, 1280, 5376, 9472, 13568};

    k_prep<<<dim3(2533), 256, 0, stream>>>(
        (const uint32_t*)in_data,
        fl[1], fl[2], fl[3], fl[4], fl[5], fl[6], Wd,
        bl[1], bl[2], bl[3], bl[4], bl[5], bl[6],
        wbuf, wdbuf, bbuf, flag);

    const int mt4 = (Bc + 63) / 64;
    const int mt32 = (Bc + 31) / 32;

    for (int b_off = 0; b_off < Bfull; b_off += Bc) {
        k_stage0<<<dim3(Bc * 64), 256, 0, stream>>>(in_data, filt, bias0, bufA, flag, b_off);

        __hip_bfloat16* cur = bufA;
        __hip_bfloat16* nxt = bufB;
        for (int lvl = 1; lvl <= 3; lvl++) {
            const int Nu = 1 << lvl;
            const int H  = 64 >> lvl;
            const int Nv_in = Nu >> 1;
            dim3 grid(Nv_in * Nv_in * H * H * mt4);
            k_level4<<<grid, 256, 0, stream>>>(cur, wbuf + w_off[lvl],
                bbuf + b_off_tab[lvl], nxt, Nu, H, Bc, mt4);
            __hip_bfloat16* tmp = cur; cur = nxt; nxt = tmp;
        }

        k_f456<<<dim3(64 * mt32), 256, 0, stream>>>(cur,
            wbuf + w_off[4], wbuf + w_off[5], wbuf + w_off[6], wdbuf,
            bbuf + b_off_tab[4], bbuf + b_off_tab[5], bbuf + b_off_tab[6],
            d_out, flag, Bc, b_off, mt32);
    }
}